// Round 6
// baseline (1495.699 us; speedup 1.0000x reference)
//
#include <hip/hip_runtime.h>

typedef __bf16 bf16x8 __attribute__((ext_vector_type(8)));
typedef float  f32x4  __attribute__((ext_vector_type(4)));

#define AS1 __attribute__((address_space(1)))
#define AS3 __attribute__((address_space(3)))
#define NB 512
#define MAGICF 0x1337BEEFu

__device__ __forceinline__ float bf2f(ushort u) {
    union { unsigned int i; float f; } v; v.i = ((unsigned int)u) << 16; return v.f;
}
__device__ __forceinline__ ushort f2bf(float f) {
    union { float f; unsigned int i; } v; v.f = f;
    unsigned int i = v.i;
    unsigned int r = i + 0x7FFFu + ((i >> 16) & 1u);   // RNE
    return (ushort)(r >> 16);
}
__device__ __forceinline__ float bflo(unsigned int u) { return bf2f((ushort)(u & 0xFFFFu)); }
__device__ __forceinline__ float bfhi(unsigned int u) { return bf2f((ushort)(u >> 16)); }

__device__ __forceinline__ bool sniff_inline(const ushort* __restrict__ x) {
    const int lane = threadIdx.x & 63;
    int cnt = 0;
    #pragma unroll
    for (int r = 0; r < 4; r++) {
        const ushort u = x[lane + r * 64];
        const int e = (u >> 7) & 0xFF;
        if ((u & 0x7FFF) == 0 || (e >= 112 && e <= 141)) cnt++;
    }
    #pragma unroll
    for (int o = 32; o > 0; o >>= 1) cnt += __shfl_xor(cnt, o);
    return cnt >= 224;
}

// ---------------------------------------------------------------------------
// GEMM tile body (one BMxBN tile): C = act(A@W^T + bias). ACT: 0 none, 1 gelu
// ---------------------------------------------------------------------------
template<int BM, int BN, int ACT, bool HASB, bool WF32, bool WBF16>
__device__ void gemm_body(const ushort* __restrict__ A, const ushort* __restrict__ W,
                          const ushort* __restrict__ bias,
                          float* __restrict__ Cf, ushort* __restrict__ Cb,
                          int N, int K, int lda, int m0, int n0,
                          ushort* As, ushort* Bs)
{
    constexpr int WMT = BM / 32;
    constexpr int WNT = BN / 32;
    const int tid  = threadIdx.x;
    const int wave = tid >> 6;
    const int lane = tid & 63;
    const int wm = (wave >> 1) * (BM / 2);
    const int wn = (wave & 1) * (BN / 2);
    const int lrow = lane & 15;
    const int quad = lane >> 4;

    f32x4 acc[WMT][WNT];
    #pragma unroll
    for (int i = 0; i < WMT; i++)
        #pragma unroll
        for (int j = 0; j < WNT; j++)
            #pragma unroll
            for (int r = 0; r < 4; r++) acc[i][j][r] = 0.f;

    for (int k0 = 0; k0 < K; k0 += 32) {
        #pragma unroll
        for (int t = 0; t < BM / 64; t++) {
            const int inst = t * 4 + wave;
            const int row  = inst * 16 + (lane >> 2);
            const int sub  = lane & 3;
            const ushort* gp = A + (size_t)(m0 + row) * lda + (k0 + sub * 8);
            __builtin_amdgcn_global_load_lds((AS1 void*)(void*)gp,
                                             (AS3 void*)(As + inst * 512), 16, 0, 0);
        }
        #pragma unroll
        for (int t = 0; t < BN / 64; t++) {
            const int inst = t * 4 + wave;
            const int row  = inst * 16 + (lane >> 2);
            const int sub  = lane & 3;
            const ushort* gp = W + (size_t)(n0 + row) * K + (k0 + sub * 8);
            __builtin_amdgcn_global_load_lds((AS1 void*)(void*)gp,
                                             (AS3 void*)(Bs + inst * 512), 16, 0, 0);
        }
        __syncthreads();
        bf16x8 afr[WMT], bfr[WNT];
        #pragma unroll
        for (int i = 0; i < WMT; i++)
            afr[i] = *(const bf16x8*)&As[(wm + i * 16 + lrow) * 32 + quad * 8];
        #pragma unroll
        for (int j = 0; j < WNT; j++)
            bfr[j] = *(const bf16x8*)&Bs[(wn + j * 16 + lrow) * 32 + quad * 8];
        #pragma unroll
        for (int i = 0; i < WMT; i++)
            #pragma unroll
            for (int j = 0; j < WNT; j++)
                acc[i][j] = __builtin_amdgcn_mfma_f32_16x16x32_bf16(afr[i], bfr[j], acc[i][j], 0, 0, 0);
        __syncthreads();
    }

    // C/D layout: col(n)=lane&15, row(m)=quad*4+reg
    #pragma unroll
    for (int i = 0; i < WMT; i++) {
        const int gm = m0 + wm + i * 16 + quad * 4;
        #pragma unroll
        for (int j = 0; j < WNT; j++) {
            const int gn = n0 + wn + j * 16 + lrow;
            const float bv = HASB ? bf2f(bias[gn]) : 0.f;
            #pragma unroll
            for (int r = 0; r < 4; r++) {
                float v = acc[i][j][r] + bv;
                if (ACT == 1) v = 0.5f * v * (1.f + erff(v * 0.70710678118654752f));
                const size_t off = (size_t)(gm + r) * N + gn;
                if (WF32)  Cf[off] = v;
                if (WBF16) Cb[off] = f2bf(v);
            }
        }
    }
}

// ---------------------------------------------------------------------------
struct MegaArgs {
    const void* src[20];
    int off[20];
    int total;
    char* ws;
    void* dout;
};

__global__ __launch_bounds__(256, 2) void mega_k(MegaArgs a)
{
    __shared__ __align__(16) ushort smem[8192];   // 16 KB, aliased per phase
    const int tid = threadIdx.x;
    const int bid = blockIdx.x;
    unsigned int* ctr = (unsigned int*)a.ws;
    const ushort* sx = (const ushort*)a.src[0];
    const bool fl = sniff_inline(sx);             // input dtype: 1=bf16, 0=f32

    // ---- barrier init (ws is poisoned 0xAA each call; block 0 re-inits) ----
    if (bid == 0) {
        if (tid < 62) ctr[tid] = 0;
        __syncthreads();
        __threadfence();
        if (tid == 0)
            __hip_atomic_store(&ctr[62], MAGICF, __ATOMIC_RELEASE, __HIP_MEMORY_SCOPE_AGENT);
    } else {
        if (tid == 0) {
            while (__hip_atomic_load(&ctr[62], __ATOMIC_ACQUIRE, __HIP_MEMORY_SCOPE_AGENT) != MAGICF)
                __builtin_amdgcn_s_sleep(8);
        }
        __syncthreads();
        __threadfence();
    }

    auto gbar = [&](int idx) {
        __syncthreads();
        __threadfence();
        if (tid == 0) {
            __hip_atomic_fetch_add(&ctr[idx], 1u, __ATOMIC_RELAXED, __HIP_MEMORY_SCOPE_AGENT);
            while (__hip_atomic_load(&ctr[idx], __ATOMIC_RELAXED, __HIP_MEMORY_SCOPE_AGENT) < NB)
                __builtin_amdgcn_s_sleep(4);
        }
        __syncthreads();
        __threadfence();
    };

    // ---- workspace layout ----
    ushort* canon   = (ushort*)(a.ws + 256);
    ushort* xpw_pad = (ushort*)(a.ws + 6291456);   // [64,512] bf16
    ushort* xz      = (ushort*)(a.ws + 8388608);   // [8192,1024] bf16
    ushort* xc      = (ushort*)(a.ws + 25165824);  // [8192,512] bf16 (y in-place later)
    float*  xdbl    = (float*)(a.ws + 33554432);   // 4 x [8192,64] f32 split-K quarters
    float*  summ    = (float*)(a.ws + 41943040);   // [4,64,32,512] f32
    float*  sout    = (float*)(a.ws + 58720256);   // [8192,256] f32
    float*  y1f     = (float*)(a.ws + 67108864);   // [8192,256] f32
    ushort* y1b     = (ushort*)(a.ws + 75497472);  // [8192,256] bf16
    ushort* f1      = (ushort*)(a.ws + 79691776);  // [8192,1024] bf16
    float*  ffn     = (float*)(a.ws + 96468992);   // [8192,256] f32

    const ushort* cx   = canon + a.off[0];
    const ushort* cipw = canon + a.off[1];
    const ushort* cipb = canon + a.off[2];
    const ushort* ccw  = canon + a.off[3];
    const ushort* ccb  = canon + a.off[4];
    const ushort* cdtw = canon + a.off[6];
    const ushort* cdtb = canon + a.off[7];
    const ushort* calog= canon + a.off[8];
    const ushort* cdssm= canon + a.off[9];
    const ushort* copw = canon + a.off[10];
    const ushort* copb = canon + a.off[11];
    const ushort* cln1g= canon + a.off[12];
    const ushort* cln1b= canon + a.off[13];
    const ushort* cf1w = canon + a.off[14];
    const ushort* cf1b = canon + a.off[15];
    const ushort* cf2w = canon + a.off[16];
    const ushort* cf2b = canon + a.off[17];
    const ushort* cln2g= canon + a.off[18];
    const ushort* cln2b= canon + a.off[19];

    // ================= P0: canonicalize inputs to bf16 (+ xpw pad) =========
    for (int i = bid * 256 + tid; i < a.total + 8192; i += NB * 256) {
        if (i >= a.total) { xpw_pad[24576 + (i - a.total)] = 0; continue; }
        int s = 0;
        #pragma unroll
        for (int t = 1; t < 20; t++) if (i >= a.off[t]) s = t;
        const int li = i - a.off[s];
        ushort v;
        if (fl) v = ((const ushort*)a.src[s])[li];
        else    v = f2bf(((const float*)a.src[s])[li]);
        canon[i] = v;
        if (s == 5) xpw_pad[li] = v;
    }
    gbar(0);

    // ================= P1: in_proj  xz = x @ ipw^T + ipb ====================
    gemm_body<128, 128, 0, true, false, true>(
        cx, cipw, cipb, nullptr, xz, 1024, 256, 256,
        (bid >> 3) * 128, (bid & 7) * 128, smem, smem + 4096);
    gbar(1);

    // ================= P2: depthwise causal conv + SiLU -> xc ==============
    for (int it = 0; it < 4; it++) {
        const int idx = (bid * 4 + it) * 256 + tid;
        const int t  = idx >> 6;
        const int d8 = (idx & 63) * 8;
        const int l  = t & 2047;
        ushort wl[32];
        *(uint4*)&wl[0]  = *(const uint4*)&ccw[d8 * 4];
        *(uint4*)&wl[8]  = *(const uint4*)&ccw[d8 * 4 + 8];
        *(uint4*)&wl[16] = *(const uint4*)&ccw[d8 * 4 + 16];
        *(uint4*)&wl[24] = *(const uint4*)&ccw[d8 * 4 + 24];
        ushort bl[8];
        *(uint4*)&bl[0] = *(const uint4*)&ccb[d8];
        float acc[8];
        #pragma unroll
        for (int j = 0; j < 8; j++) acc[j] = bf2f(bl[j]);
        #pragma unroll
        for (int k = 0; k < 4; k++) {
            const int ls = l - 3 + k;
            if (ls >= 0) {
                ushort xl[8];
                *(uint4*)&xl[0] = *(const uint4*)&xz[(size_t)(t - 3 + k) * 1024 + d8];
                #pragma unroll
                for (int j = 0; j < 8; j++) acc[j] += bf2f(xl[j]) * bf2f(wl[j * 4 + k]);
            }
        }
        ushort ol[8];
        #pragma unroll
        for (int j = 0; j < 8; j++) {
            const float s = acc[j] / (1.f + __expf(-acc[j]));
            ol[j] = f2bf(s);
        }
        *(uint4*)&xc[(size_t)idx * 8] = *(uint4*)&ol[0];
    }
    gbar(2);

    // ================= P3: xdbl = xc @ xpw_pad^T (4-way split-K) ===========
    {
        ushort* As = smem;
        ushort* Bs = smem + 2048;
        const int wave = tid >> 6, lane = tid & 63;
        const int m0   = (bid & 127) * 64;
        const int kbeg = (bid >> 7) * 128;
        const int wm = (wave >> 1) * 32, wn = (wave & 1) * 32;
        const int lrow = lane & 15, quad = lane >> 4;
        f32x4 acc[2][2];
        #pragma unroll
        for (int i = 0; i < 2; i++)
            #pragma unroll
            for (int j = 0; j < 2; j++)
                #pragma unroll
                for (int r = 0; r < 4; r++) acc[i][j][r] = 0.f;
        for (int k0 = kbeg; k0 < kbeg + 128; k0 += 32) {
            const int row = wave * 16 + (lane >> 2);
            const int sub = lane & 3;
            const ushort* gpa = xc + (size_t)(m0 + row) * 512 + (k0 + sub * 8);
            __builtin_amdgcn_global_load_lds((AS1 void*)(void*)gpa,
                                             (AS3 void*)(As + wave * 512), 16, 0, 0);
            const ushort* gpb = xpw_pad + (size_t)row * 512 + (k0 + sub * 8);
            __builtin_amdgcn_global_load_lds((AS1 void*)(void*)gpb,
                                             (AS3 void*)(Bs + wave * 512), 16, 0, 0);
            __syncthreads();
            bf16x8 afr[2], bfr[2];
            #pragma unroll
            for (int i = 0; i < 2; i++)
                afr[i] = *(const bf16x8*)&As[(wm + i * 16 + lrow) * 32 + quad * 8];
            #pragma unroll
            for (int j = 0; j < 2; j++)
                bfr[j] = *(const bf16x8*)&Bs[(wn + j * 16 + lrow) * 32 + quad * 8];
            #pragma unroll
            for (int i = 0; i < 2; i++)
                #pragma unroll
                for (int j = 0; j < 2; j++)
                    acc[i][j] = __builtin_amdgcn_mfma_f32_16x16x32_bf16(afr[i], bfr[j], acc[i][j], 0, 0, 0);
            __syncthreads();
        }
        float* out = xdbl + (size_t)(bid >> 7) * 524288;
        #pragma unroll
        for (int i = 0; i < 2; i++) {
            const int gm = m0 + wm + i * 16 + quad * 4;
            #pragma unroll
            for (int j = 0; j < 2; j++) {
                const int gn = wn + j * 16 + lrow;
                #pragma unroll
                for (int r = 0; r < 4; r++)
                    out[(size_t)(gm + r) * 64 + gn] = acc[i][j][r];
            }
        }
    }
    gbar(3);

    // ================= P4: scan pass 1 (dt inline) ==========================
    {
        float* XD = (float*)smem;   // [32 steps][32]: 0..15 dt-cols, 16..31 B
        const int c = (bid >> 1) & 63, b = bid >> 7;
        const int t0 = b * 2048 + c * 32;
        for (int e = tid; e < 1024; e += 256) {
            const size_t idx = (size_t)(t0 + (e >> 5)) * 64 + (e & 31);
            XD[e] = xdbl[idx] + xdbl[idx + 524288] + xdbl[idx + 1048576] + xdbl[idx + 1572864];
        }
        __syncthreads();
        const int d = (bid & 1) * 256 + tid;
        const uint4 w0 = *(const uint4*)&cdtw[d * 16];
        const uint4 w1 = *(const uint4*)&cdtw[d * 16 + 8];
        const float wd[16] = { bflo(w0.x), bfhi(w0.x), bflo(w0.y), bfhi(w0.y),
                               bflo(w0.z), bfhi(w0.z), bflo(w0.w), bfhi(w0.w),
                               bflo(w1.x), bfhi(w1.x), bflo(w1.y), bfhi(w1.y),
                               bflo(w1.z), bfhi(w1.z), bflo(w1.w), bfhi(w1.w) };
        const float dtbv = bf2f(cdtb[d]);
        float A[16], h[16];
        #pragma unroll
        for (int n = 0; n < 16; n++) {
            A[n] = -__expf(bf2f(calog[d * 16 + n]));
            h[n] = 0.f;
        }
        float sdt = 0.f;
        for (int i = 0; i < 32; i++) {
            const float* Xr = &XD[i * 32];
            float s = dtbv;
            #pragma unroll
            for (int k = 0; k < 16; k++) s += Xr[k] * wd[k];
            const float dtv = (s > 15.f) ? s : __logf(1.f + __expf(s));
            const float xiv = bf2f(xc[(size_t)(t0 + i) * 512 + d]);
            const float dx = dtv * xiv;
            sdt += dtv;
            #pragma unroll
            for (int n = 0; n < 16; n++) {
                const float da = __expf(dtv * A[n]);
                h[n] = da * h[n] + dx * Xr[16 + n];
            }
        }
        const size_t base = ((size_t)(b * 64 + c) * 32) * 512 + d;
        #pragma unroll
        for (int n = 0; n < 16; n++) summ[base + (size_t)n * 512] = __expf(A[n] * sdt);
        #pragma unroll
        for (int n = 0; n < 16; n++) summ[base + (size_t)(16 + n) * 512] = h[n];
    }
    gbar(4);

    // ================= P5: sequential combine (128 active blocks) ==========
    if (bid < 128) {
        const int b = bid >> 5, n = (bid >> 1) & 15;
        const int d = (bid & 1) * 256 + tid;
        float h = 0.f;
        for (int c = 0; c < 64; c++) {
            const size_t sb = ((size_t)((b * 64 + c) * 32 + n)) * 512 + d;
            const float p  = summ[sb];
            const float hl = summ[sb + 8192];
            summ[sb] = h;
            h = p * h + hl;
        }
    }
    gbar(5);

    // ================= P6: scan pass 2 (replay, gate, y in-place) ==========
    {
        float* XD = (float*)smem;   // [32][48]: dt cols, B, C
        const int c = (bid >> 1) & 63, b = bid >> 7;
        const int t0 = b * 2048 + c * 32;
        for (int e = tid; e < 1536; e += 256) {
            const size_t idx = (size_t)(t0 + (e / 48)) * 64 + (e % 48);
            XD[e] = xdbl[idx] + xdbl[idx + 524288] + xdbl[idx + 1048576] + xdbl[idx + 1572864];
        }
        __syncthreads();
        const int d = (bid & 1) * 256 + tid;
        const uint4 w0 = *(const uint4*)&cdtw[d * 16];
        const uint4 w1 = *(const uint4*)&cdtw[d * 16 + 8];
        const float wd[16] = { bflo(w0.x), bfhi(w0.x), bflo(w0.y), bfhi(w0.y),
                               bflo(w0.z), bfhi(w0.z), bflo(w0.w), bfhi(w0.w),
                               bflo(w1.x), bfhi(w1.x), bflo(w1.y), bfhi(w1.y),
                               bflo(w1.z), bfhi(w1.z), bflo(w1.w), bfhi(w1.w) };
        const float dtbv = bf2f(cdtb[d]);
        float A[16], h[16];
        #pragma unroll
        for (int n = 0; n < 16; n++) A[n] = -__expf(bf2f(calog[d * 16 + n]));
        const size_t base = ((size_t)(b * 64 + c) * 32) * 512 + d;
        #pragma unroll
        for (int n = 0; n < 16; n++) h[n] = summ[base + (size_t)n * 512];
        const float Dv = bf2f(cdssm[d]);
        for (int i = 0; i < 32; i++) {
            const int t = t0 + i;
            const float* Xr = &XD[i * 48];
            float s = dtbv;
            #pragma unroll
            for (int k = 0; k < 16; k++) s += Xr[k] * wd[k];
            const float dtv = (s > 15.f) ? s : __logf(1.f + __expf(s));
            const float xiv = bf2f(xc[(size_t)t * 512 + d]);
            const float dx = dtv * xiv;
            float yv = 0.f;
            #pragma unroll
            for (int n = 0; n < 16; n++) {
                const float da = __expf(dtv * A[n]);
                h[n] = da * h[n] + dx * Xr[16 + n];
                yv += h[n] * Xr[32 + n];
            }
            yv += xiv * Dv;
            const float zv = bf2f(xz[(size_t)t * 1024 + 512 + d]);
            yv *= zv / (1.f + __expf(-zv));
            xc[(size_t)t * 512 + d] = f2bf(yv);   // same thread, same addr
        }
    }
    gbar(6);

    // ================= P7: out_proj -> sout (f32) ==========================
    gemm_body<64, 64, 0, true, true, false>(
        xc, copw, copb, sout, nullptr, 256, 512, 512,
        (bid >> 2) * 64, (bid & 3) * 64, smem, smem + 2048);
    gbar(7);

    // ================= P8: y1 = LN(x + sout) ===============================
    for (int it = 0; it < 4; it++) {
        const int w = tid >> 6, l = tid & 63;
        const int t = (bid * 4 + it) * 4 + w;
        const size_t base = (size_t)t * 256 + l * 4;
        float v[4];
        if (fl) {
            const uint2 xr = *(const uint2*)((const ushort*)a.src[0] + base);
            v[0] = bflo(xr.x); v[1] = bfhi(xr.x); v[2] = bflo(xr.y); v[3] = bfhi(xr.y);
        } else {
            const float4 xr = *(const float4*)((const float*)a.src[0] + base);
            v[0] = xr.x; v[1] = xr.y; v[2] = xr.z; v[3] = xr.w;
        }
        const float4 sv = *(const float4*)&sout[base];
        v[0] += sv.x; v[1] += sv.y; v[2] += sv.z; v[3] += sv.w;
        float s = v[0] + v[1] + v[2] + v[3];
        #pragma unroll
        for (int o = 32; o > 0; o >>= 1) s += __shfl_xor(s, o);
        const float mean = s * (1.f / 256.f);
        float q = 0.f;
        #pragma unroll
        for (int j = 0; j < 4; j++) { const float dv = v[j] - mean; q += dv * dv; }
        #pragma unroll
        for (int o = 32; o > 0; o >>= 1) q += __shfl_xor(q, o);
        const float r = rsqrtf(q * (1.f / 256.f) + 1e-5f);
        const uint2 gv = *(const uint2*)&cln1g[l * 4];
        const uint2 bv = *(const uint2*)&cln1b[l * 4];
        const float gf[4] = { bflo(gv.x), bfhi(gv.x), bflo(gv.y), bfhi(gv.y) };
        const float bf[4] = { bflo(bv.x), bfhi(bv.x), bflo(bv.y), bfhi(bv.y) };
        float4 of; float* op = (float*)&of;
        ushort ob[4];
        #pragma unroll
        for (int j = 0; j < 4; j++) {
            const float o2 = (v[j] - mean) * r * gf[j] + bf[j];
            op[j] = o2; ob[j] = f2bf(o2);
        }
        *(float4*)&y1f[base] = of;
        *(uint2*)&y1b[base] = *(uint2*)&ob[0];
    }
    gbar(8);

    // ================= P9: fc1 + gelu -> f1 ================================
    gemm_body<128, 128, 1, true, false, true>(
        y1b, cf1w, cf1b, nullptr, f1, 1024, 256, 256,
        (bid >> 3) * 128, (bid & 7) * 128, smem, smem + 4096);
    gbar(9);

    // ================= P10: fc2 + gelu -> ffn (f32) ========================
    gemm_body<64, 64, 1, true, true, false>(
        f1, cf2w, cf2b, ffn, nullptr, 256, 1024, 1024,
        (bid >> 2) * 64, (bid & 3) * 64, smem, smem + 2048);
    gbar(10);

    // ================= P11: out = LN(y1 + ffn) -> d_out ====================
    for (int it = 0; it < 4; it++) {
        const int w = tid >> 6, l = tid & 63;
        const int t = (bid * 4 + it) * 4 + w;
        const size_t base = (size_t)t * 256 + l * 4;
        const float4 av = *(const float4*)&y1f[base];
        const float4 fv = *(const float4*)&ffn[base];
        float v[4] = { av.x + fv.x, av.y + fv.y, av.z + fv.z, av.w + fv.w };
        float s = v[0] + v[1] + v[2] + v[3];
        #pragma unroll
        for (int o = 32; o > 0; o >>= 1) s += __shfl_xor(s, o);
        const float mean = s * (1.f / 256.f);
        float q = 0.f;
        #pragma unroll
        for (int j = 0; j < 4; j++) { const float dv = v[j] - mean; q += dv * dv; }
        #pragma unroll
        for (int o = 32; o > 0; o >>= 1) q += __shfl_xor(q, o);
        const float r = rsqrtf(q * (1.f / 256.f) + 1e-5f);
        const uint2 gv = *(const uint2*)&cln2g[l * 4];
        const uint2 bv = *(const uint2*)&cln2b[l * 4];
        const float gf[4] = { bflo(gv.x), bfhi(gv.x), bflo(gv.y), bfhi(gv.y) };
        const float bf[4] = { bflo(bv.x), bfhi(bv.x), bflo(bv.y), bfhi(bv.y) };
        if (fl) {
            ushort ob[4];
            #pragma unroll
            for (int j = 0; j < 4; j++) ob[j] = f2bf((v[j] - mean) * r * gf[j] + bf[j]);
            *(uint2*)((ushort*)a.dout + base) = *(uint2*)&ob[0];
        } else {
            float4 of; float* op = (float*)&of;
            #pragma unroll
            for (int j = 0; j < 4; j++) op[j] = (v[j] - mean) * r * gf[j] + bf[j];
            *(float4*)((float*)a.dout + base) = of;
        }
    }

    // ---- final arrive; last block resets barrier state for safe replay ----
    __syncthreads();
    __threadfence();
    if (tid == 0) {
        const unsigned int old =
            __hip_atomic_fetch_add(&ctr[11], 1u, __ATOMIC_RELAXED, __HIP_MEMORY_SCOPE_AGENT);
        if (old == NB - 1) {
            for (int i = 0; i < 11; i++) ctr[i] = 0;
            __hip_atomic_store(&ctr[62], 0u, __ATOMIC_RELEASE, __HIP_MEMORY_SCOPE_AGENT);
            __threadfence();
        }
    }
}

// ---------------------------------------------------------------------------
extern "C" void kernel_launch(void* const* d_in, const int* in_sizes, int n_in,
                              void* d_out, int out_size, void* d_ws, size_t ws_size,
                              hipStream_t stream)
{
    static const int coff[20] = {
        0,        2097152,  2359296,  2360320,  2362368,
        2362880,  2387456,  2395648,  2396160,  2404352,
        2404864,  2535936,  2536192,  2536448,  2536704,
        2798848,  2799872,  3062016,  3062272,  3062528 };
    static const int ctot = 3062784;

    MegaArgs a;
    for (int i = 0; i < 20; i++) { a.src[i] = d_in[i]; a.off[i] = coff[i]; }
    a.total = ctot;
    a.ws = (char*)d_ws;
    a.dout = d_out;

    mega_k<<<NB, 256, 0, stream>>>(a);
}

// Round 7
// 571.813 us; speedup vs baseline: 2.6157x; 2.6157x over previous
//
#include <hip/hip_runtime.h>

typedef __bf16 bf16x8 __attribute__((ext_vector_type(8)));
typedef float  f32x4  __attribute__((ext_vector_type(4)));

#define AS1 __attribute__((address_space(1)))
#define AS3 __attribute__((address_space(3)))
#define NB 512
#define MAGICF 0x1337BEEFu

__device__ __forceinline__ float bf2f(ushort u) {
    union { unsigned int i; float f; } v; v.i = ((unsigned int)u) << 16; return v.f;
}
__device__ __forceinline__ ushort f2bf(float f) {
    union { float f; unsigned int i; } v; v.f = f;
    unsigned int i = v.i;
    unsigned int r = i + 0x7FFFu + ((i >> 16) & 1u);   // RNE
    return (ushort)(r >> 16);
}
__device__ __forceinline__ float bflo(unsigned int u) { return bf2f((ushort)(u & 0xFFFFu)); }
__device__ __forceinline__ float bfhi(unsigned int u) { return bf2f((ushort)(u >> 16)); }

__device__ __forceinline__ bool sniff_inline(const ushort* __restrict__ x) {
    const int lane = threadIdx.x & 63;
    int cnt = 0;
    #pragma unroll
    for (int r = 0; r < 4; r++) {
        const ushort u = x[lane + r * 64];
        const int e = (u >> 7) & 0xFF;
        if ((u & 0x7FFF) == 0 || (e >= 112 && e <= 141)) cnt++;
    }
    #pragma unroll
    for (int o = 32; o > 0; o >>= 1) cnt += __shfl_xor(cnt, o);
    return cnt >= 224;
}

// ---------------------------------------------------------------------------
// GEMM tile body. ACOH: stage A via coherent (L1/L2-bypassing) loads instead
// of global_load_lds — needed when A was rewritten by a previous phase.
// ---------------------------------------------------------------------------
template<int BM, int BN, int ACT, bool HASB, bool WF32, bool WBF16, bool ACOH>
__device__ void gemm_body(const ushort* __restrict__ A, const ushort* __restrict__ W,
                          const ushort* __restrict__ bias,
                          float* __restrict__ Cf, ushort* __restrict__ Cb,
                          int N, int K, int lda, int m0, int n0,
                          ushort* As, ushort* Bs)
{
    constexpr int WMT = BM / 32;
    constexpr int WNT = BN / 32;
    const int tid  = threadIdx.x;
    const int wave = tid >> 6;
    const int lane = tid & 63;
    const int wm = (wave >> 1) * (BM / 2);
    const int wn = (wave & 1) * (BN / 2);
    const int lrow = lane & 15;
    const int quad = lane >> 4;

    f32x4 acc[WMT][WNT];
    #pragma unroll
    for (int i = 0; i < WMT; i++)
        #pragma unroll
        for (int j = 0; j < WNT; j++)
            #pragma unroll
            for (int r = 0; r < 4; r++) acc[i][j][r] = 0.f;

    for (int k0 = 0; k0 < K; k0 += 32) {
        if (ACOH) {
            // coherent A staging: BM*16 uints, row-major [row][16 uints]
            #pragma unroll
            for (int u = 0; u < (BM * 16) / 256; u++) {
                const int e = u * 256 + tid;
                const int row = e >> 4, c2 = e & 15;
                const unsigned* gp = (const unsigned*)(A + (size_t)(m0 + row) * lda + k0) + c2;
                const unsigned val = __hip_atomic_load((unsigned*)gp, __ATOMIC_RELAXED,
                                                       __HIP_MEMORY_SCOPE_AGENT);
                *((unsigned*)As + row * 16 + c2) = val;
            }
        } else {
            #pragma unroll
            for (int t = 0; t < BM / 64; t++) {
                const int inst = t * 4 + wave;
                const int row  = inst * 16 + (lane >> 2);
                const int sub  = lane & 3;
                const ushort* gp = A + (size_t)(m0 + row) * lda + (k0 + sub * 8);
                __builtin_amdgcn_global_load_lds((AS1 void*)(void*)gp,
                                                 (AS3 void*)(As + inst * 512), 16, 0, 0);
            }
        }
        #pragma unroll
        for (int t = 0; t < BN / 64; t++) {
            const int inst = t * 4 + wave;
            const int row  = inst * 16 + (lane >> 2);
            const int sub  = lane & 3;
            const ushort* gp = W + (size_t)(n0 + row) * K + (k0 + sub * 8);
            __builtin_amdgcn_global_load_lds((AS1 void*)(void*)gp,
                                             (AS3 void*)(Bs + inst * 512), 16, 0, 0);
        }
        __syncthreads();
        bf16x8 afr[WMT], bfr[WNT];
        #pragma unroll
        for (int i = 0; i < WMT; i++)
            afr[i] = *(const bf16x8*)&As[(wm + i * 16 + lrow) * 32 + quad * 8];
        #pragma unroll
        for (int j = 0; j < WNT; j++)
            bfr[j] = *(const bf16x8*)&Bs[(wn + j * 16 + lrow) * 32 + quad * 8];
        #pragma unroll
        for (int i = 0; i < WMT; i++)
            #pragma unroll
            for (int j = 0; j < WNT; j++)
                acc[i][j] = __builtin_amdgcn_mfma_f32_16x16x32_bf16(afr[i], bfr[j], acc[i][j], 0, 0, 0);
        __syncthreads();
    }

    // C/D layout: col(n)=lane&15, row(m)=quad*4+reg
    #pragma unroll
    for (int i = 0; i < WMT; i++) {
        const int gm = m0 + wm + i * 16 + quad * 4;
        #pragma unroll
        for (int j = 0; j < WNT; j++) {
            const int gn = n0 + wn + j * 16 + lrow;
            const float bv = HASB ? bf2f(bias[gn]) : 0.f;
            #pragma unroll
            for (int r = 0; r < 4; r++) {
                float v = acc[i][j][r] + bv;
                if (ACT == 1) v = 0.5f * v * (1.f + erff(v * 0.70710678118654752f));
                const size_t off = (size_t)(gm + r) * N + gn;
                if (WF32)  Cf[off] = v;
                if (WBF16) Cb[off] = f2bf(v);
            }
        }
    }
}

// ---------------------------------------------------------------------------
struct MegaArgs {
    const void* src[20];
    int off[20];
    int total;
    char* ws;
    void* dout;
};

__global__ __launch_bounds__(256, 2) void mega_k(MegaArgs a)
{
    __shared__ __align__(16) ushort smem[8192];   // 16 KB, aliased per phase
    const int tid = threadIdx.x;
    const int bid = blockIdx.x;
    unsigned int* ctr = (unsigned int*)a.ws;      // control block: first 4 KB
    const ushort* sx = (const ushort*)a.src[0];
    const bool fl = sniff_inline(sx);             // input dtype: 1=bf16, 0=f32

    // ---- barrier init (ws poisoned 0xAA each call; block 0 re-inits) ------
    // ctr[p]          p<16  : arrival counters
    // ctr[16+p*8+x]         : per-XCD election slots
    // ctr[144+p]            : release (XCDs-flushed) counters
    // ctr[256]              : magic init flag
    if (bid == 0) {
        if (tid < 160)
            __hip_atomic_store(&ctr[tid], 0u, __ATOMIC_RELAXED, __HIP_MEMORY_SCOPE_AGENT);
        __syncthreads();
        if (tid == 0)
            __hip_atomic_store(&ctr[256], MAGICF, __ATOMIC_RELEASE, __HIP_MEMORY_SCOPE_AGENT);
    } else {
        if (tid == 0) {
            while (__hip_atomic_load(&ctr[256], __ATOMIC_ACQUIRE, __HIP_MEMORY_SCOPE_AGENT) != MAGICF)
                __builtin_amdgcn_s_sleep(8);
        }
        __syncthreads();
    }

    // XCD-aware grid barrier: 8 wbl2 (one per XCD) instead of 512+.
    auto gbar = [&](int p) {
        __syncthreads();   // drains vmcnt: this block's stores are in its L2
        if (tid == 0) {
            __hip_atomic_fetch_add(&ctr[p], 1u, __ATOMIC_RELAXED, __HIP_MEMORY_SCOPE_AGENT);
            while (__hip_atomic_load(&ctr[p], __ATOMIC_RELAXED, __HIP_MEMORY_SCOPE_AGENT) < NB)
                __builtin_amdgcn_s_sleep(2);
            unsigned xcc;
            asm volatile("s_getreg_b32 %0, hwreg(HW_REG_XCC_ID)" : "=s"(xcc));
            if (__hip_atomic_fetch_add(&ctr[16 + p * 8 + (xcc & 7)], 1u,
                                       __ATOMIC_RELAXED, __HIP_MEMORY_SCOPE_AGENT) == 0u) {
                __builtin_amdgcn_fence(__ATOMIC_RELEASE, "agent");   // one wbl2/XCD
                __hip_atomic_fetch_add(&ctr[144 + p], 1u, __ATOMIC_RELAXED, __HIP_MEMORY_SCOPE_AGENT);
            }
            while (__hip_atomic_load(&ctr[144 + p], __ATOMIC_RELAXED, __HIP_MEMORY_SCOPE_AGENT) < 8u)
                __builtin_amdgcn_s_sleep(2);
            // single acquire: inv for this block + compiler ordering
            (void)__hip_atomic_load(&ctr[144 + p], __ATOMIC_ACQUIRE, __HIP_MEMORY_SCOPE_AGENT);
        }
        __syncthreads();
    };

    // ---- workspace layout (canon moved to +4096 for the control block) ----
    ushort* canon   = (ushort*)(a.ws + 4096);
    ushort* xpw_pad = (ushort*)(a.ws + 6291456);   // [64,512] bf16
    ushort* xz      = (ushort*)(a.ws + 8388608);   // [8192,1024] bf16
    ushort* xc      = (ushort*)(a.ws + 25165824);  // [8192,512] bf16 (y in-place later)
    float*  xdbl    = (float*)(a.ws + 33554432);   // 4 x [8192,64] f32 split-K quarters
    float*  summ    = (float*)(a.ws + 41943040);   // [4,64,32,512] f32
    float*  sout    = (float*)(a.ws + 58720256);   // [8192,256] f32
    float*  y1f     = (float*)(a.ws + 67108864);   // [8192,256] f32
    ushort* y1b     = (ushort*)(a.ws + 75497472);  // [8192,256] bf16
    ushort* f1      = (ushort*)(a.ws + 79691776);  // [8192,1024] bf16
    float*  ffn     = (float*)(a.ws + 96468992);   // [8192,256] f32

    const ushort* cx   = canon + a.off[0];
    const ushort* cipw = canon + a.off[1];
    const ushort* cipb = canon + a.off[2];
    const ushort* ccw  = canon + a.off[3];
    const ushort* ccb  = canon + a.off[4];
    const ushort* cdtw = canon + a.off[6];
    const ushort* cdtb = canon + a.off[7];
    const ushort* calog= canon + a.off[8];
    const ushort* cdssm= canon + a.off[9];
    const ushort* copw = canon + a.off[10];
    const ushort* copb = canon + a.off[11];
    const ushort* cln1g= canon + a.off[12];
    const ushort* cln1b= canon + a.off[13];
    const ushort* cf1w = canon + a.off[14];
    const ushort* cf1b = canon + a.off[15];
    const ushort* cf2w = canon + a.off[16];
    const ushort* cf2b = canon + a.off[17];
    const ushort* cln2g= canon + a.off[18];
    const ushort* cln2b= canon + a.off[19];

    // ================= P0: canonicalize inputs to bf16 (+ xpw pad) =========
    for (int i = bid * 256 + tid; i < a.total + 8192; i += NB * 256) {
        if (i >= a.total) { xpw_pad[24576 + (i - a.total)] = 0; continue; }
        int s = 0;
        #pragma unroll
        for (int t = 1; t < 20; t++) if (i >= a.off[t]) s = t;
        const int li = i - a.off[s];
        ushort v;
        if (fl) v = ((const ushort*)a.src[s])[li];
        else    v = f2bf(((const float*)a.src[s])[li]);
        canon[i] = v;
        if (s == 5) xpw_pad[li] = v;
    }
    gbar(0);

    // ================= P1: in_proj  xz = x @ ipw^T + ipb ====================
    gemm_body<128, 128, 0, true, false, true, false>(
        cx, cipw, cipb, nullptr, xz, 1024, 256, 256,
        (bid >> 3) * 128, (bid & 7) * 128, smem, smem + 4096);
    gbar(1);

    // ================= P2: depthwise causal conv + SiLU -> xc ==============
    for (int it = 0; it < 4; it++) {
        const int idx = (bid * 4 + it) * 256 + tid;
        const int t  = idx >> 6;
        const int d8 = (idx & 63) * 8;
        const int l  = t & 2047;
        ushort wl[32];
        *(uint4*)&wl[0]  = *(const uint4*)&ccw[d8 * 4];
        *(uint4*)&wl[8]  = *(const uint4*)&ccw[d8 * 4 + 8];
        *(uint4*)&wl[16] = *(const uint4*)&ccw[d8 * 4 + 16];
        *(uint4*)&wl[24] = *(const uint4*)&ccw[d8 * 4 + 24];
        ushort bl[8];
        *(uint4*)&bl[0] = *(const uint4*)&ccb[d8];
        float acc[8];
        #pragma unroll
        for (int j = 0; j < 8; j++) acc[j] = bf2f(bl[j]);
        #pragma unroll
        for (int k = 0; k < 4; k++) {
            const int ls = l - 3 + k;
            if (ls >= 0) {
                ushort xl[8];
                *(uint4*)&xl[0] = *(const uint4*)&xz[(size_t)(t - 3 + k) * 1024 + d8];
                #pragma unroll
                for (int j = 0; j < 8; j++) acc[j] += bf2f(xl[j]) * bf2f(wl[j * 4 + k]);
            }
        }
        ushort ol[8];
        #pragma unroll
        for (int j = 0; j < 8; j++) {
            const float s = acc[j] / (1.f + __expf(-acc[j]));
            ol[j] = f2bf(s);
        }
        *(uint4*)&xc[(size_t)idx * 8] = *(uint4*)&ol[0];
    }
    gbar(2);

    // ================= P3: xdbl = xc @ xpw_pad^T (4-way split-K) ===========
    {
        ushort* As = smem;
        ushort* Bs = smem + 2048;
        const int wave = tid >> 6, lane = tid & 63;
        const int m0   = (bid & 127) * 64;
        const int kbeg = (bid >> 7) * 128;
        const int wm = (wave >> 1) * 32, wn = (wave & 1) * 32;
        const int lrow = lane & 15, quad = lane >> 4;
        f32x4 acc[2][2];
        #pragma unroll
        for (int i = 0; i < 2; i++)
            #pragma unroll
            for (int j = 0; j < 2; j++)
                #pragma unroll
                for (int r = 0; r < 4; r++) acc[i][j][r] = 0.f;
        for (int k0 = kbeg; k0 < kbeg + 128; k0 += 32) {
            const int row = wave * 16 + (lane >> 2);
            const int sub = lane & 3;
            const ushort* gpa = xc + (size_t)(m0 + row) * 512 + (k0 + sub * 8);
            __builtin_amdgcn_global_load_lds((AS1 void*)(void*)gpa,
                                             (AS3 void*)(As + wave * 512), 16, 0, 0);
            const ushort* gpb = xpw_pad + (size_t)row * 512 + (k0 + sub * 8);
            __builtin_amdgcn_global_load_lds((AS1 void*)(void*)gpb,
                                             (AS3 void*)(Bs + wave * 512), 16, 0, 0);
            __syncthreads();
            bf16x8 afr[2], bfr[2];
            #pragma unroll
            for (int i = 0; i < 2; i++)
                afr[i] = *(const bf16x8*)&As[(wm + i * 16 + lrow) * 32 + quad * 8];
            #pragma unroll
            for (int j = 0; j < 2; j++)
                bfr[j] = *(const bf16x8*)&Bs[(wn + j * 16 + lrow) * 32 + quad * 8];
            #pragma unroll
            for (int i = 0; i < 2; i++)
                #pragma unroll
                for (int j = 0; j < 2; j++)
                    acc[i][j] = __builtin_amdgcn_mfma_f32_16x16x32_bf16(afr[i], bfr[j], acc[i][j], 0, 0, 0);
            __syncthreads();
        }
        float* out = xdbl + (size_t)(bid >> 7) * 524288;
        #pragma unroll
        for (int i = 0; i < 2; i++) {
            const int gm = m0 + wm + i * 16 + quad * 4;
            #pragma unroll
            for (int j = 0; j < 2; j++) {
                const int gn = wn + j * 16 + lrow;
                #pragma unroll
                for (int r = 0; r < 4; r++)
                    out[(size_t)(gm + r) * 64 + gn] = acc[i][j][r];
            }
        }
    }
    gbar(3);

    // ================= P4: scan pass 1 (dt inline) ==========================
    {
        float* XD = (float*)smem;   // [32 steps][32]: 0..15 dt-cols, 16..31 B
        const int c = (bid >> 1) & 63, b = bid >> 7;
        const int t0 = b * 2048 + c * 32;
        for (int e = tid; e < 1024; e += 256) {
            const size_t idx = (size_t)(t0 + (e >> 5)) * 64 + (e & 31);
            XD[e] = xdbl[idx] + xdbl[idx + 524288] + xdbl[idx + 1048576] + xdbl[idx + 1572864];
        }
        __syncthreads();
        const int d = (bid & 1) * 256 + tid;
        const uint4 w0 = *(const uint4*)&cdtw[d * 16];
        const uint4 w1 = *(const uint4*)&cdtw[d * 16 + 8];
        const float wd[16] = { bflo(w0.x), bfhi(w0.x), bflo(w0.y), bfhi(w0.y),
                               bflo(w0.z), bfhi(w0.z), bflo(w0.w), bfhi(w0.w),
                               bflo(w1.x), bfhi(w1.x), bflo(w1.y), bfhi(w1.y),
                               bflo(w1.z), bfhi(w1.z), bflo(w1.w), bfhi(w1.w) };
        const float dtbv = bf2f(cdtb[d]);
        float A[16], h[16];
        #pragma unroll
        for (int n = 0; n < 16; n++) {
            A[n] = -__expf(bf2f(calog[d * 16 + n]));
            h[n] = 0.f;
        }
        float sdt = 0.f;
        for (int i = 0; i < 32; i++) {
            const float* Xr = &XD[i * 32];
            float s = dtbv;
            #pragma unroll
            for (int k = 0; k < 16; k++) s += Xr[k] * wd[k];
            const float dtv = (s > 15.f) ? s : __logf(1.f + __expf(s));
            const float xiv = bf2f(xc[(size_t)(t0 + i) * 512 + d]);
            const float dx = dtv * xiv;
            sdt += dtv;
            #pragma unroll
            for (int n = 0; n < 16; n++) {
                const float da = __expf(dtv * A[n]);
                h[n] = da * h[n] + dx * Xr[16 + n];
            }
        }
        const size_t base = ((size_t)(b * 64 + c) * 32) * 512 + d;
        #pragma unroll
        for (int n = 0; n < 16; n++) summ[base + (size_t)n * 512] = __expf(A[n] * sdt);
        #pragma unroll
        for (int n = 0; n < 16; n++) summ[base + (size_t)(16 + n) * 512] = h[n];
    }
    gbar(4);

    // ================= P5: sequential combine (128 active blocks) ==========
    if (bid < 128) {
        const int b = bid >> 5, n = (bid >> 1) & 15;
        const int d = (bid & 1) * 256 + tid;
        float h = 0.f;
        for (int c = 0; c < 64; c++) {
            const size_t sb = ((size_t)((b * 64 + c) * 32 + n)) * 512 + d;
            const float p  = summ[sb];
            const float hl = summ[sb + 8192];
            summ[sb] = h;
            h = p * h + hl;
        }
    }
    gbar(5);

    // ================= P6: scan pass 2 (replay, gate, y in-place) ==========
    {
        float* XD = (float*)smem;   // [32][48]: dt cols, B, C
        const int c = (bid >> 1) & 63, b = bid >> 7;
        const int t0 = b * 2048 + c * 32;
        for (int e = tid; e < 1536; e += 256) {
            const size_t idx = (size_t)(t0 + (e / 48)) * 64 + (e % 48);
            XD[e] = xdbl[idx] + xdbl[idx + 524288] + xdbl[idx + 1048576] + xdbl[idx + 1572864];
        }
        __syncthreads();
        const int d = (bid & 1) * 256 + tid;
        const uint4 w0 = *(const uint4*)&cdtw[d * 16];
        const uint4 w1 = *(const uint4*)&cdtw[d * 16 + 8];
        const float wd[16] = { bflo(w0.x), bfhi(w0.x), bflo(w0.y), bfhi(w0.y),
                               bflo(w0.z), bfhi(w0.z), bflo(w0.w), bfhi(w0.w),
                               bflo(w1.x), bfhi(w1.x), bflo(w1.y), bfhi(w1.y),
                               bflo(w1.z), bfhi(w1.z), bflo(w1.w), bfhi(w1.w) };
        const float dtbv = bf2f(cdtb[d]);
        float A[16], h[16];
        #pragma unroll
        for (int n = 0; n < 16; n++) A[n] = -__expf(bf2f(calog[d * 16 + n]));
        const size_t base = ((size_t)(b * 64 + c) * 32) * 512 + d;
        #pragma unroll
        for (int n = 0; n < 16; n++)
            h[n] = __hip_atomic_load(&summ[base + (size_t)n * 512],
                                     __ATOMIC_RELAXED, __HIP_MEMORY_SCOPE_AGENT);
        const float Dv = bf2f(cdssm[d]);
        for (int i = 0; i < 32; i++) {
            const int t = t0 + i;
            const float* Xr = &XD[i * 48];
            float s = dtbv;
            #pragma unroll
            for (int k = 0; k < 16; k++) s += Xr[k] * wd[k];
            const float dtv = (s > 15.f) ? s : __logf(1.f + __expf(s));
            const float xiv = bf2f(xc[(size_t)t * 512 + d]);
            const float dx = dtv * xiv;
            float yv = 0.f;
            #pragma unroll
            for (int n = 0; n < 16; n++) {
                const float da = __expf(dtv * A[n]);
                h[n] = da * h[n] + dx * Xr[16 + n];
                yv += h[n] * Xr[32 + n];
            }
            yv += xiv * Dv;
            const float zv = bf2f(xz[(size_t)t * 1024 + 512 + d]);
            yv *= zv / (1.f + __expf(-zv));
            xc[(size_t)t * 512 + d] = f2bf(yv);   // same thread, same addr
        }
    }
    gbar(6);

    // ================= P7: out_proj -> sout (f32); A=xc rewritten -> ACOH ==
    gemm_body<64, 64, 0, true, true, false, true>(
        xc, copw, copb, sout, nullptr, 256, 512, 512,
        (bid >> 2) * 64, (bid & 3) * 64, smem, smem + 2048);
    gbar(7);

    // ================= P8: y1 = LN(x + sout) ===============================
    for (int it = 0; it < 4; it++) {
        const int w = tid >> 6, l = tid & 63;
        const int t = (bid * 4 + it) * 4 + w;
        const size_t base = (size_t)t * 256 + l * 4;
        float v[4];
        if (fl) {
            const uint2 xr = *(const uint2*)((const ushort*)a.src[0] + base);
            v[0] = bflo(xr.x); v[1] = bfhi(xr.x); v[2] = bflo(xr.y); v[3] = bfhi(xr.y);
        } else {
            const float4 xr = *(const float4*)((const float*)a.src[0] + base);
            v[0] = xr.x; v[1] = xr.y; v[2] = xr.z; v[3] = xr.w;
        }
        const float4 sv = *(const float4*)&sout[base];
        v[0] += sv.x; v[1] += sv.y; v[2] += sv.z; v[3] += sv.w;
        float s = v[0] + v[1] + v[2] + v[3];
        #pragma unroll
        for (int o = 32; o > 0; o >>= 1) s += __shfl_xor(s, o);
        const float mean = s * (1.f / 256.f);
        float q = 0.f;
        #pragma unroll
        for (int j = 0; j < 4; j++) { const float dv = v[j] - mean; q += dv * dv; }
        #pragma unroll
        for (int o = 32; o > 0; o >>= 1) q += __shfl_xor(q, o);
        const float r = rsqrtf(q * (1.f / 256.f) + 1e-5f);
        const uint2 gv = *(const uint2*)&cln1g[l * 4];
        const uint2 bv = *(const uint2*)&cln1b[l * 4];
        const float gf[4] = { bflo(gv.x), bfhi(gv.x), bflo(gv.y), bfhi(gv.y) };
        const float bf[4] = { bflo(bv.x), bfhi(bv.x), bflo(bv.y), bfhi(bv.y) };
        float4 of; float* op = (float*)&of;
        ushort ob[4];
        #pragma unroll
        for (int j = 0; j < 4; j++) {
            const float o2 = (v[j] - mean) * r * gf[j] + bf[j];
            op[j] = o2; ob[j] = f2bf(o2);
        }
        *(float4*)&y1f[base] = of;
        *(uint2*)&y1b[base] = *(uint2*)&ob[0];
    }
    gbar(8);

    // ================= P9: fc1 + gelu -> f1 ================================
    gemm_body<128, 128, 1, true, false, true, false>(
        y1b, cf1w, cf1b, nullptr, f1, 1024, 256, 256,
        (bid >> 3) * 128, (bid & 7) * 128, smem, smem + 4096);
    gbar(9);

    // ================= P10: fc2 + gelu -> ffn (f32) ========================
    gemm_body<64, 64, 1, true, true, false, false>(
        f1, cf2w, cf2b, ffn, nullptr, 256, 1024, 1024,
        (bid >> 2) * 64, (bid & 3) * 64, smem, smem + 2048);
    gbar(10);

    // ================= P11: out = LN(y1 + ffn) -> d_out ====================
    for (int it = 0; it < 4; it++) {
        const int w = tid >> 6, l = tid & 63;
        const int t = (bid * 4 + it) * 4 + w;
        const size_t base = (size_t)t * 256 + l * 4;
        const float4 av = *(const float4*)&y1f[base];
        const float4 fv = *(const float4*)&ffn[base];
        float v[4] = { av.x + fv.x, av.y + fv.y, av.z + fv.z, av.w + fv.w };
        float s = v[0] + v[1] + v[2] + v[3];
        #pragma unroll
        for (int o = 32; o > 0; o >>= 1) s += __shfl_xor(s, o);
        const float mean = s * (1.f / 256.f);
        float q = 0.f;
        #pragma unroll
        for (int j = 0; j < 4; j++) { const float dv = v[j] - mean; q += dv * dv; }
        #pragma unroll
        for (int o = 32; o > 0; o >>= 1) q += __shfl_xor(q, o);
        const float r = rsqrtf(q * (1.f / 256.f) + 1e-5f);
        const uint2 gv = *(const uint2*)&cln2g[l * 4];
        const uint2 bv = *(const uint2*)&cln2b[l * 4];
        const float gf[4] = { bflo(gv.x), bfhi(gv.x), bflo(gv.y), bfhi(gv.y) };
        const float bf[4] = { bflo(bv.x), bfhi(bv.x), bflo(bv.y), bfhi(bv.y) };
        if (fl) {
            ushort ob[4];
            #pragma unroll
            for (int j = 0; j < 4; j++) ob[j] = f2bf((v[j] - mean) * r * gf[j] + bf[j]);
            *(uint2*)((ushort*)a.dout + base) = *(uint2*)&ob[0];
        } else {
            float4 of; float* op = (float*)&of;
            #pragma unroll
            for (int j = 0; j < 4; j++) op[j] = (v[j] - mean) * r * gf[j] + bf[j];
            *(float4*)((float*)a.dout + base) = of;
        }
    }
    // no reset needed: harness re-poisons ws before every launch
}

// ---------------------------------------------------------------------------
extern "C" void kernel_launch(void* const* d_in, const int* in_sizes, int n_in,
                              void* d_out, int out_size, void* d_ws, size_t ws_size,
                              hipStream_t stream)
{
    static const int coff[20] = {
        0,        2097152,  2359296,  2360320,  2362368,
        2362880,  2387456,  2395648,  2396160,  2404352,
        2404864,  2535936,  2536192,  2536448,  2536704,
        2798848,  2799872,  3062016,  3062272,  3062528 };
    static const int ctot = 3062784;

    MegaArgs a;
    for (int i = 0; i < 20; i++) { a.src[i] = d_in[i]; a.off[i] = coff[i]; }
    a.total = ctot;
    a.ws = (char*)d_ws;
    a.dout = d_out;

    mega_k<<<NB, 256, 0, stream>>>(a);
}

// Round 8
// 251.724 us; speedup vs baseline: 5.9418x; 2.2716x over previous
//
#include <hip/hip_runtime.h>

typedef __bf16 bf16x8 __attribute__((ext_vector_type(8)));
typedef float  f32x4  __attribute__((ext_vector_type(4)));

#define AS1 __attribute__((address_space(1)))
#define AS3 __attribute__((address_space(3)))

__device__ __forceinline__ float bf2f(ushort u) {
    union { unsigned int i; float f; } v; v.i = ((unsigned int)u) << 16; return v.f;
}
__device__ __forceinline__ ushort f2bf(float f) {
    union { float f; unsigned int i; } v; v.f = f;
    unsigned int i = v.i;
    unsigned int r = i + 0x7FFFu + ((i >> 16) & 1u);   // RNE
    return (ushort)(r >> 16);
}
__device__ __forceinline__ float bflo(unsigned int u) { return bf2f((ushort)(u & 0xFFFFu)); }
__device__ __forceinline__ float bfhi(unsigned int u) { return bf2f((ushort)(u >> 16)); }

// wave-level inline dtype sniff: 1 = bf16 inputs, 0 = f32
__device__ __forceinline__ bool sniff_inline(const ushort* __restrict__ x) {
    const int lane = threadIdx.x & 63;
    int cnt = 0;
    #pragma unroll
    for (int r = 0; r < 4; r++) {
        const ushort u = x[lane + r * 64];
        const int e = (u >> 7) & 0xFF;
        if ((u & 0x7FFF) == 0 || (e >= 112 && e <= 141)) cnt++;
    }
    #pragma unroll
    for (int o = 32; o > 0; o >>= 1) cnt += __shfl_xor(cnt, o);
    return cnt >= 224;
}

// ---------------------------------------------------------------------------
// canonicalize all inputs into packed bf16 region; also writes xpw_pad [64,512]
// ---------------------------------------------------------------------------
struct CanonArgs {
    const void* src[20];
    int off[20];
    int total;
};

__launch_bounds__(256)
__global__ void canon_k(CanonArgs a, ushort* __restrict__ dst, ushort* __restrict__ xpw_pad,
                        const ushort* __restrict__ sniffx)
{
    const int i = blockIdx.x * 256 + threadIdx.x;
    if (i >= a.total) {
        const int j = i - a.total;
        if (j < 8192) xpw_pad[24576 + j] = 0;   // pad rows 48..63
        return;
    }
    const bool fl = sniff_inline(sniffx);
    int s = 0;
    #pragma unroll
    for (int t = 1; t < 20; t++) if (i >= a.off[t]) s = t;
    const int li = i - a.off[s];
    ushort v;
    if (fl) v = ((const ushort*)a.src[s])[li];
    else    v = f2bf(((const float*)a.src[s])[li]);
    dst[i] = v;
    if (s == 5) xpw_pad[li] = v;                // xpw rows 0..47
}

// ---------------------------------------------------------------------------
// GEMM: C[M,N] = act(A[M,K](bf16,lda) @ W[N,K]^T(bf16) + bias[N]). ACT 0/1=gelu
// ---------------------------------------------------------------------------
template<int BM, int BN, int ACT, bool HASB, bool WF32, bool WBF16>
__launch_bounds__(256, 2)
__global__ void gemm_bt(const ushort* __restrict__ A, const ushort* __restrict__ W,
                        const ushort* __restrict__ bias,
                        float* __restrict__ Cf, ushort* __restrict__ Cb,
                        int M, int N, int K, int lda)
{
    constexpr int WMT = BM / 32;
    constexpr int WNT = BN / 32;
    __shared__ __align__(16) ushort As[BM * 32];
    __shared__ __align__(16) ushort Bs[BN * 32];
    const int tid  = threadIdx.x;
    const int wave = tid >> 6;
    const int lane = tid & 63;
    const int m0 = blockIdx.x * BM;
    const int n0 = blockIdx.y * BN;
    const int wm = (wave >> 1) * (BM / 2);
    const int wn = (wave & 1) * (BN / 2);
    const int lrow = lane & 15;
    const int quad = lane >> 4;

    f32x4 acc[WMT][WNT];
    #pragma unroll
    for (int i = 0; i < WMT; i++)
        #pragma unroll
        for (int j = 0; j < WNT; j++)
            #pragma unroll
            for (int r = 0; r < 4; r++) acc[i][j][r] = 0.f;

    for (int k0 = 0; k0 < K; k0 += 32) {
        #pragma unroll
        for (int t = 0; t < BM / 64; t++) {
            const int inst = t * 4 + wave;
            const int row  = inst * 16 + (lane >> 2);
            const int sub  = lane & 3;
            const ushort* gp = A + (size_t)(m0 + row) * lda + (k0 + sub * 8);
            __builtin_amdgcn_global_load_lds((AS1 void*)(void*)gp,
                                             (AS3 void*)(As + inst * 512), 16, 0, 0);
        }
        #pragma unroll
        for (int t = 0; t < BN / 64; t++) {
            const int inst = t * 4 + wave;
            const int row  = inst * 16 + (lane >> 2);
            const int sub  = lane & 3;
            const ushort* gp = W + (size_t)(n0 + row) * K + (k0 + sub * 8);
            __builtin_amdgcn_global_load_lds((AS1 void*)(void*)gp,
                                             (AS3 void*)(Bs + inst * 512), 16, 0, 0);
        }
        __syncthreads();
        bf16x8 afr[WMT], bfr[WNT];
        #pragma unroll
        for (int i = 0; i < WMT; i++)
            afr[i] = *(const bf16x8*)&As[(wm + i * 16 + lrow) * 32 + quad * 8];
        #pragma unroll
        for (int j = 0; j < WNT; j++)
            bfr[j] = *(const bf16x8*)&Bs[(wn + j * 16 + lrow) * 32 + quad * 8];
        #pragma unroll
        for (int i = 0; i < WMT; i++)
            #pragma unroll
            for (int j = 0; j < WNT; j++)
                acc[i][j] = __builtin_amdgcn_mfma_f32_16x16x32_bf16(afr[i], bfr[j], acc[i][j], 0, 0, 0);
        __syncthreads();
    }

    // C/D layout: col(n)=lane&15, row(m)=quad*4+reg
    #pragma unroll
    for (int i = 0; i < WMT; i++) {
        const int gm = m0 + wm + i * 16 + quad * 4;
        #pragma unroll
        for (int j = 0; j < WNT; j++) {
            const int gn = n0 + wn + j * 16 + lrow;
            const float bv = HASB ? bf2f(bias[gn]) : 0.f;
            #pragma unroll
            for (int r = 0; r < 4; r++) {
                float v = acc[i][j][r] + bv;
                if (ACT == 1) v = 0.5f * v * (1.f + erff(v * 0.70710678118654752f));
                const size_t off = (size_t)(gm + r) * N + gn;
                if (WF32)  Cf[off] = v;
                if (WBF16) Cb[off] = f2bf(v);
            }
        }
    }
}

// ---------------------------------------------------------------------------
// fused conv(DC=4)+SiLU for 16 tokens -> LDS + global xc, then
// xdbl[16 tok, 64] = xcs @ xpw_pad^T (K=512) from LDS.  grid 512.
// ---------------------------------------------------------------------------
__launch_bounds__(256, 2)
__global__ void convxdbl_k(const ushort* __restrict__ xz, const ushort* __restrict__ cw,
                           const ushort* __restrict__ cb, const ushort* __restrict__ xpw_pad,
                           ushort* __restrict__ xc, float* __restrict__ xdbl)
{
    __shared__ __align__(16) ushort xcs[16 * 520];   // +8 pad: bank shift 4/row
    __shared__ __align__(16) ushort Bs[64 * 32];
    const int tid  = threadIdx.x;
    const int wave = tid >> 6;
    const int lane = tid & 63;
    const int T0 = blockIdx.x * 16;

    // ---- conv+silu: each thread owns 8 d's across 4 token rows ----
    const int d8 = (tid & 63) * 8;
    const int tr = tid >> 6;
    ushort wl[32];
    *(uint4*)&wl[0]  = *(const uint4*)&cw[d8 * 4];
    *(uint4*)&wl[8]  = *(const uint4*)&cw[d8 * 4 + 8];
    *(uint4*)&wl[16] = *(const uint4*)&cw[d8 * 4 + 16];
    *(uint4*)&wl[24] = *(const uint4*)&cw[d8 * 4 + 24];
    ushort bl[8];
    *(uint4*)&bl[0] = *(const uint4*)&cb[d8];
    #pragma unroll
    for (int it = 0; it < 4; it++) {
        const int trow = it * 4 + tr;
        const int t = T0 + trow;
        const int l = t & 2047;
        float acc[8];
        #pragma unroll
        for (int j = 0; j < 8; j++) acc[j] = bf2f(bl[j]);
        #pragma unroll
        for (int k = 0; k < 4; k++) {
            const int ls = l - 3 + k;
            if (ls >= 0) {
                ushort xl[8];
                *(uint4*)&xl[0] = *(const uint4*)&xz[(size_t)(t - 3 + k) * 1024 + d8];
                #pragma unroll
                for (int j = 0; j < 8; j++) acc[j] += bf2f(xl[j]) * bf2f(wl[j * 4 + k]);
            }
        }
        ushort ol[8];
        #pragma unroll
        for (int j = 0; j < 8; j++) {
            const float s = acc[j] / (1.f + __expf(-acc[j]));
            ol[j] = f2bf(s);
        }
        *(uint4*)&xcs[trow * 520 + d8] = *(uint4*)&ol[0];
        *(uint4*)&xc[(size_t)t * 512 + d8] = *(uint4*)&ol[0];
    }
    __syncthreads();

    // ---- xdbl: 16x64, K=512; wave handles out cols wn..wn+15 ----
    const int lrow = lane & 15;
    const int quad = lane >> 4;
    const int wn = wave * 16;
    f32x4 acc2 = {0.f, 0.f, 0.f, 0.f};
    for (int k0 = 0; k0 < 512; k0 += 32) {
        {
            const int row = wn + (lane >> 2);
            const int sub = lane & 3;
            const ushort* gp = xpw_pad + (size_t)row * 512 + (k0 + sub * 8);
            __builtin_amdgcn_global_load_lds((AS1 void*)(void*)gp,
                                             (AS3 void*)(Bs + wave * 512), 16, 0, 0);
        }
        __syncthreads();
        const bf16x8 afr = *(const bf16x8*)&xcs[lrow * 520 + k0 + quad * 8];
        const bf16x8 bfr = *(const bf16x8*)&Bs[wave * 512 + lrow * 32 + quad * 8];
        acc2 = __builtin_amdgcn_mfma_f32_16x16x32_bf16(afr, bfr, acc2, 0, 0, 0);
        __syncthreads();
    }
    #pragma unroll
    for (int r = 0; r < 4; r++)
        xdbl[(size_t)(T0 + quad * 4 + r) * 64 + wn + lrow] = acc2[r];
}

// ---------------------------------------------------------------------------
// chunked scan, 64 chunks x 32 steps; dt computed inline from xdbl[:, :16]
// ---------------------------------------------------------------------------
__launch_bounds__(256)
__global__ void scan1_k(const float* __restrict__ xdbl, const ushort* __restrict__ xc,
                        const ushort* __restrict__ dtw, const ushort* __restrict__ dtb,
                        const ushort* __restrict__ Alog, float* __restrict__ summ)
{
    __shared__ float XD[32 * 32];   // [step][0..15 dt-cols, 16..31 B]
    const int tid = threadIdx.x;
    const int c = blockIdx.y, b = blockIdx.z;
    const int t0 = b * 2048 + c * 32;
    for (int e = tid; e < 1024; e += 256)
        XD[e] = xdbl[(size_t)(t0 + (e >> 5)) * 64 + (e & 31)];
    __syncthreads();
    const int d = blockIdx.x * 256 + tid;

    const uint4 w0 = *(const uint4*)&dtw[d * 16];
    const uint4 w1 = *(const uint4*)&dtw[d * 16 + 8];
    const float wd[16] = { bflo(w0.x), bfhi(w0.x), bflo(w0.y), bfhi(w0.y),
                           bflo(w0.z), bfhi(w0.z), bflo(w0.w), bfhi(w0.w),
                           bflo(w1.x), bfhi(w1.x), bflo(w1.y), bfhi(w1.y),
                           bflo(w1.z), bfhi(w1.z), bflo(w1.w), bfhi(w1.w) };
    const float dtbv = bf2f(dtb[d]);

    float A[16], h[16];
    #pragma unroll
    for (int n = 0; n < 16; n++) {
        A[n] = -__expf(bf2f(Alog[d * 16 + n]));
        h[n] = 0.f;
    }
    float sdt = 0.f;
    for (int i = 0; i < 32; i++) {
        const float* Xr = &XD[i * 32];
        float s = dtbv;
        #pragma unroll
        for (int k = 0; k < 16; k++) s += Xr[k] * wd[k];
        const float dtv = (s > 15.f) ? s : __logf(1.f + __expf(s));
        const float xiv = bf2f(xc[(size_t)(t0 + i) * 512 + d]);
        const float dx = dtv * xiv;
        sdt += dtv;
        #pragma unroll
        for (int n = 0; n < 16; n++) {
            const float da = __expf(dtv * A[n]);
            h[n] = da * h[n] + dx * Xr[16 + n];
        }
    }
    const size_t base = ((size_t)(b * 64 + c) * 32) * 512 + d;
    #pragma unroll
    for (int n = 0; n < 16; n++) summ[base + (size_t)n * 512] = __expf(A[n] * sdt);
    #pragma unroll
    for (int n = 0; n < 16; n++) summ[base + (size_t)(16 + n) * 512] = h[n];
}

// sequential combine, register-batched (loads pipelined, chain in regs)
__launch_bounds__(512)
__global__ void combine_k(float* __restrict__ summ)
{
    const int b = blockIdx.x >> 4, n = blockIdx.x & 15;
    const int d = threadIdx.x;
    float h = 0.f;
    #pragma unroll
    for (int half = 0; half < 2; half++) {
        float p[32], hl[32], ho[32];
        #pragma unroll
        for (int c2 = 0; c2 < 32; c2++) {
            const size_t sb = ((size_t)((b * 64 + half * 32 + c2) * 32 + n)) * 512 + d;
            p[c2]  = summ[sb];
            hl[c2] = summ[sb + 8192];
        }
        #pragma unroll
        for (int c2 = 0; c2 < 32; c2++) {
            ho[c2] = h;
            h = p[c2] * h + hl[c2];
        }
        #pragma unroll
        for (int c2 = 0; c2 < 32; c2++) {
            const size_t sb = ((size_t)((b * 64 + half * 32 + c2) * 32 + n)) * 512 + d;
            summ[sb] = ho[c2];
        }
    }
}

// pass2: replay chunk from h_in; dt inline; writes y in-place over xc
__launch_bounds__(256)
__global__ void scan2_k(const float* __restrict__ xdbl, ushort* xc,
                        const ushort* __restrict__ dtw, const ushort* __restrict__ dtb,
                        const ushort* __restrict__ Alog, const float* __restrict__ summ,
                        const ushort* __restrict__ xz, const ushort* __restrict__ Dssm)
{
    __shared__ float XD[32 * 48];   // [step][0..15 dt, 16..31 B, 32..47 C]
    const int tid = threadIdx.x;
    const int c = blockIdx.y, b = blockIdx.z;
    const int t0 = b * 2048 + c * 32;
    for (int e = tid; e < 1536; e += 256)
        XD[e] = xdbl[(size_t)(t0 + (e / 48)) * 64 + (e % 48)];
    __syncthreads();
    const int d = blockIdx.x * 256 + tid;

    const uint4 w0 = *(const uint4*)&dtw[d * 16];
    const uint4 w1 = *(const uint4*)&dtw[d * 16 + 8];
    const float wd[16] = { bflo(w0.x), bfhi(w0.x), bflo(w0.y), bfhi(w0.y),
                           bflo(w0.z), bfhi(w0.z), bflo(w0.w), bfhi(w0.w),
                           bflo(w1.x), bfhi(w1.x), bflo(w1.y), bfhi(w1.y),
                           bflo(w1.z), bfhi(w1.z), bflo(w1.w), bfhi(w1.w) };
    const float dtbv = bf2f(dtb[d]);

    float A[16], h[16];
    #pragma unroll
    for (int n = 0; n < 16; n++) A[n] = -__expf(bf2f(Alog[d * 16 + n]));
    const size_t base = ((size_t)(b * 64 + c) * 32) * 512 + d;
    #pragma unroll
    for (int n = 0; n < 16; n++) h[n] = summ[base + (size_t)n * 512];
    const float Dv = bf2f(Dssm[d]);

    for (int i = 0; i < 32; i++) {
        const int t = t0 + i;
        const float* Xr = &XD[i * 48];
        float s = dtbv;
        #pragma unroll
        for (int k = 0; k < 16; k++) s += Xr[k] * wd[k];
        const float dtv = (s > 15.f) ? s : __logf(1.f + __expf(s));
        const float xiv = bf2f(xc[(size_t)t * 512 + d]);
        const float dx = dtv * xiv;
        float yv = 0.f;
        #pragma unroll
        for (int n = 0; n < 16; n++) {
            const float da = __expf(dtv * A[n]);
            h[n] = da * h[n] + dx * Xr[16 + n];
            yv += h[n] * Xr[32 + n];
        }
        yv += xiv * Dv;
        const float zv = bf2f(xz[(size_t)t * 1024 + 512 + d]);
        yv *= zv / (1.f + __expf(-zv));
        xc[(size_t)t * 512 + d] = f2bf(yv);   // yb in-place (same thread+addr)
    }
}

// ---------------------------------------------------------------------------
// fused GEMM (BM=16, BN=256, grid 512) + row LayerNorm epilogue.
// MODE 0: out_proj+LN1, resid = canon x (bf16), writes y1f + y1b
// MODE 1: fc2+gelu+LN2, resid = y1f (f32), writes d_out (flag dtype)
// ---------------------------------------------------------------------------
template<int K, int ACT, int MODE>
__launch_bounds__(256, 2)
__global__ void gemm_ln16(const ushort* __restrict__ A, const ushort* __restrict__ W,
                          const ushort* __restrict__ bias,
                          const ushort* __restrict__ residb, const float* __restrict__ residf,
                          const ushort* __restrict__ g, const ushort* __restrict__ bvec,
                          float* __restrict__ y1f_out, ushort* __restrict__ y1b_out,
                          void* __restrict__ dout, const ushort* __restrict__ sniffx)
{
    __shared__ __align__(16) ushort As[16 * 32];
    __shared__ __align__(16) ushort Bs[256 * 32];
    __shared__ float redS[64], redQ[64];
    const int tid  = threadIdx.x;
    const int wave = tid >> 6;
    const int lane = tid & 63;
    const int lrow = lane & 15;
    const int quad = lane >> 4;
    const int m0 = blockIdx.x * 16;
    const int wn = wave * 64;

    f32x4 acc[4];
    #pragma unroll
    for (int j = 0; j < 4; j++)
        #pragma unroll
        for (int r = 0; r < 4; r++) acc[j][r] = 0.f;

    for (int k0 = 0; k0 < K; k0 += 32) {
        if (wave == 0) {
            const int row = lane >> 2;
            const int sub = lane & 3;
            const ushort* gp = A + (size_t)(m0 + row) * K + (k0 + sub * 8);
            __builtin_amdgcn_global_load_lds((AS1 void*)(void*)gp,
                                             (AS3 void*)(As), 16, 0, 0);
        }
        #pragma unroll
        for (int t = 0; t < 4; t++) {
            const int inst = t * 4 + wave;
            const int row  = inst * 16 + (lane >> 2);
            const int sub  = lane & 3;
            const ushort* gp = W + (size_t)row * K + (k0 + sub * 8);
            __builtin_amdgcn_global_load_lds((AS1 void*)(void*)gp,
                                             (AS3 void*)(Bs + inst * 512), 16, 0, 0);
        }
        __syncthreads();
        const bf16x8 afr = *(const bf16x8*)&As[lrow * 32 + quad * 8];
        #pragma unroll
        for (int j = 0; j < 4; j++) {
            const bf16x8 bfr = *(const bf16x8*)&Bs[(wn + j * 16 + lrow) * 32 + quad * 8];
            acc[j] = __builtin_amdgcn_mfma_f32_16x16x32_bf16(afr, bfr, acc[j], 0, 0, 0);
        }
        __syncthreads();
    }

    // epilogue: rows gm=m0+quad*4+r, cols gn=wn+j*16+lrow
    float v[4][4];
    float ps[4] = {0.f, 0.f, 0.f, 0.f}, pq[4] = {0.f, 0.f, 0.f, 0.f};
    #pragma unroll
    for (int j = 0; j < 4; j++) {
        const int gn = wn + j * 16 + lrow;
        const float bv = bf2f(bias[gn]);
        #pragma unroll
        for (int r = 0; r < 4; r++) {
            const size_t off = (size_t)(m0 + quad * 4 + r) * 256 + gn;
            float x_ = acc[j][r] + bv;
            if (ACT == 1) x_ = 0.5f * x_ * (1.f + erff(x_ * 0.70710678118654752f));
            x_ += (MODE == 0) ? bf2f(residb[off]) : residf[off];
            v[j][r] = x_;
            ps[r] += x_;
            pq[r] += x_ * x_;
        }
    }
    #pragma unroll
    for (int r = 0; r < 4; r++) {
        #pragma unroll
        for (int o = 8; o > 0; o >>= 1) {
            ps[r] += __shfl_xor(ps[r], o);
            pq[r] += __shfl_xor(pq[r], o);
        }
    }
    if (lrow == 0) {
        #pragma unroll
        for (int r = 0; r < 4; r++) {
            redS[wave * 16 + quad * 4 + r] = ps[r];
            redQ[wave * 16 + quad * 4 + r] = pq[r];
        }
    }
    __syncthreads();

    const bool fl = (MODE == 1) ? sniff_inline(sniffx) : false;
    #pragma unroll
    for (int r = 0; r < 4; r++) {
        const int row = quad * 4 + r;
        const float S = redS[row] + redS[16 + row] + redS[32 + row] + redS[48 + row];
        const float Q = redQ[row] + redQ[16 + row] + redQ[32 + row] + redQ[48 + row];
        const float mean = S * (1.f / 256.f);
        const float var  = Q * (1.f / 256.f) - mean * mean;
        const float rs   = rsqrtf(var + 1e-5f);
        #pragma unroll
        for (int j = 0; j < 4; j++) {
            const int gn = wn + j * 16 + lrow;
            const size_t off = (size_t)(m0 + row) * 256 + gn;
            const float out = (v[j][r] - mean) * rs * bf2f(g[gn]) + bf2f(bvec[gn]);
            if (MODE == 0) {
                y1f_out[off] = out;
                y1b_out[off] = f2bf(out);
            } else {
                if (fl) ((ushort*)dout)[off] = f2bf(out);
                else    ((float*)dout)[off]  = out;
            }
        }
    }
}

// ---------------------------------------------------------------------------
extern "C" void kernel_launch(void* const* d_in, const int* in_sizes, int n_in,
                              void* d_out, int out_size, void* d_ws, size_t ws_size,
                              hipStream_t stream)
{
    char* ws = (char*)d_ws;
    ushort* canon = (ushort*)(ws + 256);

    static const int coff[20] = {
        0,        2097152,  2359296,  2360320,  2362368,
        2362880,  2387456,  2395648,  2396160,  2404352,
        2404864,  2535936,  2536192,  2536448,  2536704,
        2798848,  2799872,  3062016,  3062272,  3062528 };
    static const int ctot = 3062784;

    CanonArgs ca;
    for (int i = 0; i < 20; i++) { ca.src[i] = d_in[i]; ca.off[i] = coff[i]; }
    ca.total = ctot;

    const ushort* cx   = canon + coff[0];
    const ushort* cipw = canon + coff[1];
    const ushort* cipb = canon + coff[2];
    const ushort* ccw  = canon + coff[3];
    const ushort* ccb  = canon + coff[4];
    const ushort* cdtw = canon + coff[6];
    const ushort* cdtb = canon + coff[7];
    const ushort* calog= canon + coff[8];
    const ushort* cdssm= canon + coff[9];
    const ushort* copw = canon + coff[10];
    const ushort* copb = canon + coff[11];
    const ushort* cln1g= canon + coff[12];
    const ushort* cln1b= canon + coff[13];
    const ushort* cf1w = canon + coff[14];
    const ushort* cf1b = canon + coff[15];
    const ushort* cf2w = canon + coff[16];
    const ushort* cf2b = canon + coff[17];
    const ushort* cln2g= canon + coff[18];
    const ushort* cln2b= canon + coff[19];

    ushort* xpw_pad = (ushort*)(ws + 6291456);  // [64,512] bf16
    ushort* xz      = (ushort*)(ws + 8388608);  // [8192,1024] bf16, 16 MB
    ushort* xc      = (ushort*)(ws + 25165824); // [8192,512] bf16 (yb in-place later)
    float*  xdbl    = (float*)(ws + 33554432);  // [8192,64] f32, 2 MB
    float*  summ    = (float*)(ws + 35651584);  // [4,64,32,512] f32, 16 MB
    float*  y1f     = (float*)(ws + 52428800);  // [8192,256] f32, 8 MB
    ushort* y1b     = (ushort*)(ws + 60817408); // [8192,256] bf16, 4 MB
    ushort* f1      = (ushort*)(ws + 65011712); // [8192,1024] bf16, 16 MB
    ushort* yb      = xc;
    const ushort* sx = (const ushort*)d_in[0];

    // 1. canon + xpw padding (inline sniff)
    canon_k<<<(ctot + 8192 + 255) / 256, 256, 0, stream>>>(ca, canon, xpw_pad, sx);
    // 2. in_proj: xz = x @ ipw^T + ipb
    gemm_bt<128, 128, 0, true, false, true><<<dim3(64, 8), 256, 0, stream>>>(
        cx, cipw, cipb, nullptr, xz, 8192, 1024, 256, 256);
    // 3. conv + silu + xdbl GEMM (fused, 16 tokens/block)
    convxdbl_k<<<512, 256, 0, stream>>>(xz, ccw, ccb, xpw_pad, xc, xdbl);
    // 4-6. chunked scan (dt inline)
    scan1_k<<<dim3(2, 64, 4), 256, 0, stream>>>(xdbl, xc, cdtw, cdtb, calog, summ);
    combine_k<<<64, 512, 0, stream>>>(summ);
    scan2_k<<<dim3(2, 64, 4), 256, 0, stream>>>(xdbl, xc, cdtw, cdtb, calog, summ, xz, cdssm);
    // 7. out_proj + LN1 fused -> y1f, y1b  (resid = canon x, bf16)
    gemm_ln16<512, 0, 0><<<512, 256, 0, stream>>>(
        yb, copw, copb, cx, nullptr, cln1g, cln1b, y1f, y1b, nullptr, sx);
    // 8. fc1 + gelu -> f1
    gemm_bt<128, 128, 1, true, false, true><<<dim3(64, 8), 256, 0, stream>>>(
        y1b, cf1w, cf1b, nullptr, f1, 8192, 1024, 256, 256);
    // 9. fc2 + gelu + LN2 fused -> d_out
    gemm_ln16<1024, 1, 1><<<512, 256, 0, stream>>>(
        f1, cf2w, cf2b, nullptr, y1f, cln2g, cln2b, nullptr, nullptr, d_out, sx);
}

// Round 9
// 237.379 us; speedup vs baseline: 6.3009x; 1.0604x over previous
//
#include <hip/hip_runtime.h>

typedef __bf16 bf16x8 __attribute__((ext_vector_type(8)));
typedef float  f32x4  __attribute__((ext_vector_type(4)));

#define AS1 __attribute__((address_space(1)))
#define AS3 __attribute__((address_space(3)))

__device__ __forceinline__ float bf2f(ushort u) {
    union { unsigned int i; float f; } v; v.i = ((unsigned int)u) << 16; return v.f;
}
__device__ __forceinline__ ushort f2bf(float f) {
    union { float f; unsigned int i; } v; v.f = f;
    unsigned int i = v.i;
    unsigned int r = i + 0x7FFFu + ((i >> 16) & 1u);   // RNE
    return (ushort)(r >> 16);
}
__device__ __forceinline__ float bflo(unsigned int u) { return bf2f((ushort)(u & 0xFFFFu)); }
__device__ __forceinline__ float bfhi(unsigned int u) { return bf2f((ushort)(u >> 16)); }
__device__ __forceinline__ float gelu_f(float v) {
    return 0.5f * v * (1.f + erff(v * 0.70710678118654752f));
}

// wave-level inline dtype sniff: 1 = bf16 inputs, 0 = f32
__device__ __forceinline__ bool sniff_inline(const ushort* __restrict__ x) {
    const int lane = threadIdx.x & 63;
    int cnt = 0;
    #pragma unroll
    for (int r = 0; r < 4; r++) {
        const ushort u = x[lane + r * 64];
        const int e = (u >> 7) & 0xFF;
        if ((u & 0x7FFF) == 0 || (e >= 112 && e <= 141)) cnt++;
    }
    #pragma unroll
    for (int o = 32; o > 0; o >>= 1) cnt += __shfl_xor(cnt, o);
    return cnt >= 224;
}

// ---------------------------------------------------------------------------
// canonicalize all inputs into packed bf16 region; also writes xpw_pad [64,512]
// ---------------------------------------------------------------------------
struct CanonArgs {
    const void* src[20];
    int off[20];
    int total;
};

__launch_bounds__(256)
__global__ void canon_k(CanonArgs a, ushort* __restrict__ dst, ushort* __restrict__ xpw_pad,
                        const ushort* __restrict__ sniffx)
{
    const int i = blockIdx.x * 256 + threadIdx.x;
    if (i >= a.total) {
        const int j = i - a.total;
        if (j < 8192) xpw_pad[24576 + j] = 0;   // pad rows 48..63
        return;
    }
    const bool fl = sniff_inline(sniffx);
    int s = 0;
    #pragma unroll
    for (int t = 1; t < 20; t++) if (i >= a.off[t]) s = t;
    const int li = i - a.off[s];
    ushort v;
    if (fl) v = ((const ushort*)a.src[s])[li];
    else    v = f2bf(((const float*)a.src[s])[li]);
    dst[i] = v;
    if (s == 5) xpw_pad[li] = v;                // xpw rows 0..47
}

// ---------------------------------------------------------------------------
// in_proj GEMM: xz[8192,1024] = x @ ipw^T + ipb   (proven m97-style core)
// ---------------------------------------------------------------------------
template<int BM, int BN>
__launch_bounds__(256, 2)
__global__ void gemm_bt(const ushort* __restrict__ A, const ushort* __restrict__ W,
                        const ushort* __restrict__ bias, ushort* __restrict__ Cb,
                        int N, int K)
{
    constexpr int WMT = BM / 32;
    constexpr int WNT = BN / 32;
    __shared__ __align__(16) ushort As[BM * 32];
    __shared__ __align__(16) ushort Bs[BN * 32];
    const int tid  = threadIdx.x;
    const int wave = tid >> 6;
    const int lane = tid & 63;
    const int m0 = blockIdx.x * BM;
    const int n0 = blockIdx.y * BN;
    const int wm = (wave >> 1) * (BM / 2);
    const int wn = (wave & 1) * (BN / 2);
    const int lrow = lane & 15;
    const int quad = lane >> 4;

    f32x4 acc[WMT][WNT];
    #pragma unroll
    for (int i = 0; i < WMT; i++)
        #pragma unroll
        for (int j = 0; j < WNT; j++)
            #pragma unroll
            for (int r = 0; r < 4; r++) acc[i][j][r] = 0.f;

    for (int k0 = 0; k0 < K; k0 += 32) {
        #pragma unroll
        for (int t = 0; t < BM / 64; t++) {
            const int inst = t * 4 + wave;
            const int row  = inst * 16 + (lane >> 2);
            const int sub  = lane & 3;
            const ushort* gp = A + (size_t)(m0 + row) * K + (k0 + sub * 8);
            __builtin_amdgcn_global_load_lds((AS1 void*)(void*)gp,
                                             (AS3 void*)(As + inst * 512), 16, 0, 0);
        }
        #pragma unroll
        for (int t = 0; t < BN / 64; t++) {
            const int inst = t * 4 + wave;
            const int row  = inst * 16 + (lane >> 2);
            const int sub  = lane & 3;
            const ushort* gp = W + (size_t)(n0 + row) * K + (k0 + sub * 8);
            __builtin_amdgcn_global_load_lds((AS1 void*)(void*)gp,
                                             (AS3 void*)(Bs + inst * 512), 16, 0, 0);
        }
        __syncthreads();
        bf16x8 afr[WMT], bfr[WNT];
        #pragma unroll
        for (int i = 0; i < WMT; i++)
            afr[i] = *(const bf16x8*)&As[(wm + i * 16 + lrow) * 32 + quad * 8];
        #pragma unroll
        for (int j = 0; j < WNT; j++)
            bfr[j] = *(const bf16x8*)&Bs[(wn + j * 16 + lrow) * 32 + quad * 8];
        #pragma unroll
        for (int i = 0; i < WMT; i++)
            #pragma unroll
            for (int j = 0; j < WNT; j++)
                acc[i][j] = __builtin_amdgcn_mfma_f32_16x16x32_bf16(afr[i], bfr[j], acc[i][j], 0, 0, 0);
        __syncthreads();
    }

    #pragma unroll
    for (int i = 0; i < WMT; i++) {
        const int gm = m0 + wm + i * 16 + quad * 4;
        #pragma unroll
        for (int j = 0; j < WNT; j++) {
            const int gn = n0 + wn + j * 16 + lrow;
            const float bv = bf2f(bias[gn]);
            #pragma unroll
            for (int r = 0; r < 4; r++)
                Cb[(size_t)(gm + r) * N + gn] = f2bf(acc[i][j][r] + bv);
        }
    }
}

// ---------------------------------------------------------------------------
// conv+SiLU (32 tokens, LDS) -> xdbl GEMM (LDS A, L2 B) -> scan pass 1
// grid (64 c, 4 b) x 512 threads
// ---------------------------------------------------------------------------
__launch_bounds__(512)
__global__ void convscan1_k(const ushort* __restrict__ xz, const ushort* __restrict__ cw,
                            const ushort* __restrict__ cb, const ushort* __restrict__ xpw_pad,
                            const ushort* __restrict__ dtw, const ushort* __restrict__ dtb,
                            const ushort* __restrict__ Alog,
                            float* __restrict__ xdbl, float* __restrict__ summ)
{
    __shared__ __align__(16) ushort xcs[32 * 520];
    __shared__ float XD[32 * 48];
    const int tid  = threadIdx.x;
    const int wave = tid >> 6;
    const int lane = tid & 63;
    const int lrow = lane & 15;
    const int quad = lane >> 4;
    const int c = blockIdx.x, b = blockIdx.y;
    const int t0 = b * 2048 + c * 32;

    // ---- conv + silu: thread owns 8 d's x 4 token rows ----
    {
        const int d8 = (tid & 63) * 8;
        ushort wl[32];
        *(uint4*)&wl[0]  = *(const uint4*)&cw[d8 * 4];
        *(uint4*)&wl[8]  = *(const uint4*)&cw[d8 * 4 + 8];
        *(uint4*)&wl[16] = *(const uint4*)&cw[d8 * 4 + 16];
        *(uint4*)&wl[24] = *(const uint4*)&cw[d8 * 4 + 24];
        ushort bl[8];
        *(uint4*)&bl[0] = *(const uint4*)&cb[d8];
        #pragma unroll
        for (int it = 0; it < 4; it++) {
            const int trow = it * 8 + (tid >> 6);
            const int t = t0 + trow;
            const int l = t & 2047;
            float acc[8];
            #pragma unroll
            for (int j = 0; j < 8; j++) acc[j] = bf2f(bl[j]);
            #pragma unroll
            for (int k = 0; k < 4; k++) {
                const int ls = l - 3 + k;
                if (ls >= 0) {
                    ushort xl[8];
                    *(uint4*)&xl[0] = *(const uint4*)&xz[(size_t)(t - 3 + k) * 1024 + d8];
                    #pragma unroll
                    for (int j = 0; j < 8; j++) acc[j] += bf2f(xl[j]) * bf2f(wl[j * 4 + k]);
                }
            }
            ushort ol[8];
            #pragma unroll
            for (int j = 0; j < 8; j++) {
                const float s = acc[j] / (1.f + __expf(-acc[j]));
                ol[j] = f2bf(s);
            }
            *(uint4*)&xcs[trow * 520 + d8] = *(uint4*)&ol[0];
        }
    }
    __syncthreads();

    // ---- xdbl = xcs @ xpw_pad^T: M=32, N=64, K=512; wave (mt=w>>2, nt=w&3) ----
    {
        const int mt = wave >> 2, nt = wave & 3;
        f32x4 acc = {0.f, 0.f, 0.f, 0.f};
        for (int k0 = 0; k0 < 512; k0 += 32) {
            const bf16x8 afr = *(const bf16x8*)&xcs[(mt * 16 + lrow) * 520 + k0 + quad * 8];
            const bf16x8 bfr = *(const bf16x8*)(xpw_pad + (size_t)(nt * 16 + lrow) * 512 + k0 + quad * 8);
            acc = __builtin_amdgcn_mfma_f32_16x16x32_bf16(afr, bfr, acc, 0, 0, 0);
        }
        const int col = nt * 16 + lrow;
        if (col < 48) {
            #pragma unroll
            for (int r = 0; r < 4; r++) {
                const int row = mt * 16 + quad * 4 + r;
                XD[row * 48 + col] = acc[r];
                xdbl[(size_t)(t0 + row) * 64 + col] = acc[r];
            }
        }
    }
    __syncthreads();

    // ---- scan pass 1: thread owns one d (0..511), 16 states ----
    {
        const int d = tid;
        const uint4 w0 = *(const uint4*)&dtw[d * 16];
        const uint4 w1 = *(const uint4*)&dtw[d * 16 + 8];
        const float wd[16] = { bflo(w0.x), bfhi(w0.x), bflo(w0.y), bfhi(w0.y),
                               bflo(w0.z), bfhi(w0.z), bflo(w0.w), bfhi(w0.w),
                               bflo(w1.x), bfhi(w1.x), bflo(w1.y), bfhi(w1.y),
                               bflo(w1.z), bfhi(w1.z), bflo(w1.w), bfhi(w1.w) };
        const float dtbv = bf2f(dtb[d]);
        float A[16], h[16];
        #pragma unroll
        for (int n = 0; n < 16; n++) {
            A[n] = -__expf(bf2f(Alog[d * 16 + n]));
            h[n] = 0.f;
        }
        float sdt = 0.f;
        for (int i = 0; i < 32; i++) {
            const float* Xr = &XD[i * 48];
            float s = dtbv;
            #pragma unroll
            for (int k = 0; k < 16; k++) s += Xr[k] * wd[k];
            const float dtv = (s > 15.f) ? s : __logf(1.f + __expf(s));
            const float xiv = bf2f(xcs[i * 520 + d]);
            const float dx = dtv * xiv;
            sdt += dtv;
            #pragma unroll
            for (int n = 0; n < 16; n++) {
                const float da = __expf(dtv * A[n]);
                h[n] = da * h[n] + dx * Xr[16 + n];
            }
        }
        const size_t base = ((size_t)(b * 64 + c) * 32) * 512 + d;
        #pragma unroll
        for (int n = 0; n < 16; n++) summ[base + (size_t)n * 512] = __expf(A[n] * sdt);
        #pragma unroll
        for (int n = 0; n < 16; n++) summ[base + (size_t)(16 + n) * 512] = h[n];
    }
}

// sequential combine, register-batched; overwrites p-slot with h_in
__launch_bounds__(512)
__global__ void combine_k(float* __restrict__ summ)
{
    const int b = blockIdx.x >> 4, n = blockIdx.x & 15;
    const int d = threadIdx.x;
    float h = 0.f;
    #pragma unroll
    for (int half = 0; half < 2; half++) {
        float p[32], hl[32], ho[32];
        #pragma unroll
        for (int c2 = 0; c2 < 32; c2++) {
            const size_t sb = ((size_t)((b * 64 + half * 32 + c2) * 32 + n)) * 512 + d;
            p[c2]  = summ[sb];
            hl[c2] = summ[sb + 8192];
        }
        #pragma unroll
        for (int c2 = 0; c2 < 32; c2++) {
            ho[c2] = h;
            h = p[c2] * h + hl[c2];
        }
        #pragma unroll
        for (int c2 = 0; c2 < 32; c2++) {
            const size_t sb = ((size_t)((b * 64 + half * 32 + c2) * 32 + n)) * 512 + d;
            summ[sb] = ho[c2];
        }
    }
}

// ---------------------------------------------------------------------------
// tail: conv recompute -> scan2 (y into LDS) -> out_proj+LN1 -> fc1 (quarters)
//       -> fc2 accumulate -> gelu+resid -> LN2 -> d_out.  grid (64,4) x 512
// ---------------------------------------------------------------------------
__launch_bounds__(512)
__global__ void tail_k(const ushort* __restrict__ xz, const ushort* __restrict__ cw,
                       const ushort* __restrict__ cb, const float* __restrict__ xdbl,
                       const ushort* __restrict__ dtw, const ushort* __restrict__ dtb,
                       const ushort* __restrict__ Alog, const float* __restrict__ summ,
                       const ushort* __restrict__ Dssm, const ushort* __restrict__ cx,
                       const ushort* __restrict__ opw, const ushort* __restrict__ opb,
                       const ushort* __restrict__ ln1g, const ushort* __restrict__ ln1b,
                       const ushort* __restrict__ f1w, const ushort* __restrict__ f1b,
                       const ushort* __restrict__ f2w, const ushort* __restrict__ f2b,
                       const ushort* __restrict__ ln2g, const ushort* __restrict__ ln2b,
                       void* __restrict__ dout, const ushort* __restrict__ sniffx)
{
    __shared__ __align__(16) ushort yls[32 * 520];   // xi -> y (in place); later f1q
    __shared__ float XD[32 * 48];
    __shared__ __align__(16) ushort y1bs[32 * 264];
    __shared__ float redS[8 * 32], redQ[8 * 32];
    ushort* f1q = yls;                                // alias (y dead after out_proj)

    const int tid  = threadIdx.x;
    const int wave = tid >> 6;
    const int lane = tid & 63;
    const int lrow = lane & 15;
    const int quad = lane >> 4;
    const int c = blockIdx.x, b = blockIdx.y;
    const int t0 = b * 2048 + c * 32;

    // ---- conv + silu (same as convscan1) ----
    {
        const int d8 = (tid & 63) * 8;
        ushort wl[32];
        *(uint4*)&wl[0]  = *(const uint4*)&cw[d8 * 4];
        *(uint4*)&wl[8]  = *(const uint4*)&cw[d8 * 4 + 8];
        *(uint4*)&wl[16] = *(const uint4*)&cw[d8 * 4 + 16];
        *(uint4*)&wl[24] = *(const uint4*)&cw[d8 * 4 + 24];
        ushort bl[8];
        *(uint4*)&bl[0] = *(const uint4*)&cb[d8];
        #pragma unroll
        for (int it = 0; it < 4; it++) {
            const int trow = it * 8 + (tid >> 6);
            const int t = t0 + trow;
            const int l = t & 2047;
            float acc[8];
            #pragma unroll
            for (int j = 0; j < 8; j++) acc[j] = bf2f(bl[j]);
            #pragma unroll
            for (int k = 0; k < 4; k++) {
                const int ls = l - 3 + k;
                if (ls >= 0) {
                    ushort xl[8];
                    *(uint4*)&xl[0] = *(const uint4*)&xz[(size_t)(t - 3 + k) * 1024 + d8];
                    #pragma unroll
                    for (int j = 0; j < 8; j++) acc[j] += bf2f(xl[j]) * bf2f(wl[j * 4 + k]);
                }
            }
            ushort ol[8];
            #pragma unroll
            for (int j = 0; j < 8; j++) {
                const float s = acc[j] / (1.f + __expf(-acc[j]));
                ol[j] = f2bf(s);
            }
            *(uint4*)&yls[trow * 520 + d8] = *(uint4*)&ol[0];
        }
    }
    // ---- XD staging ----
    for (int e = tid; e < 1536; e += 512)
        XD[e] = xdbl[(size_t)(t0 + (e / 48)) * 64 + (e % 48)];
    __syncthreads();

    // ---- scan pass 2: thread owns one d; y overwrites xi in LDS ----
    {
        const int d = tid;
        const uint4 w0 = *(const uint4*)&dtw[d * 16];
        const uint4 w1 = *(const uint4*)&dtw[d * 16 + 8];
        const float wd[16] = { bflo(w0.x), bfhi(w0.x), bflo(w0.y), bfhi(w0.y),
                               bflo(w0.z), bfhi(w0.z), bflo(w0.w), bfhi(w0.w),
                               bflo(w1.x), bfhi(w1.x), bflo(w1.y), bfhi(w1.y),
                               bflo(w1.z), bfhi(w1.z), bflo(w1.w), bfhi(w1.w) };
        const float dtbv = bf2f(dtb[d]);
        float A[16], h[16];
        #pragma unroll
        for (int n = 0; n < 16; n++) A[n] = -__expf(bf2f(Alog[d * 16 + n]));
        const size_t base = ((size_t)(b * 64 + c) * 32) * 512 + d;
        #pragma unroll
        for (int n = 0; n < 16; n++) h[n] = summ[base + (size_t)n * 512];
        const float Dv = bf2f(Dssm[d]);
        for (int i = 0; i < 32; i++) {
            const int t = t0 + i;
            const float* Xr = &XD[i * 48];
            float s = dtbv;
            #pragma unroll
            for (int k = 0; k < 16; k++) s += Xr[k] * wd[k];
            const float dtv = (s > 15.f) ? s : __logf(1.f + __expf(s));
            const float xiv = bf2f(yls[i * 520 + d]);
            const float dx = dtv * xiv;
            float yv = 0.f;
            #pragma unroll
            for (int n = 0; n < 16; n++) {
                const float da = __expf(dtv * A[n]);
                h[n] = da * h[n] + dx * Xr[16 + n];
                yv += h[n] * Xr[32 + n];
            }
            yv += xiv * Dv;
            const float zv = bf2f(xz[(size_t)t * 1024 + 512 + d]);
            yv *= zv / (1.f + __expf(-zv));
            yls[i * 520 + d] = f2bf(yv);   // in-place (same thread, same slot)
        }
    }
    __syncthreads();

    // ---- out_proj: M=32, N=256, K=512 from LDS y; wave -> cols wave*32.. ----
    const int n0w = wave * 32;
    f32x4 accP[2][2];
    #pragma unroll
    for (int i = 0; i < 2; i++)
        #pragma unroll
        for (int j = 0; j < 2; j++)
            #pragma unroll
            for (int r = 0; r < 4; r++) accP[i][j][r] = 0.f;
    for (int k0 = 0; k0 < 512; k0 += 32) {
        bf16x8 afr[2], bfr[2];
        #pragma unroll
        for (int i = 0; i < 2; i++)
            afr[i] = *(const bf16x8*)&yls[(i * 16 + lrow) * 520 + k0 + quad * 8];
        #pragma unroll
        for (int j = 0; j < 2; j++)
            bfr[j] = *(const bf16x8*)(opw + (size_t)(n0w + j * 16 + lrow) * 512 + k0 + quad * 8);
        #pragma unroll
        for (int i = 0; i < 2; i++)
            #pragma unroll
            for (int j = 0; j < 2; j++)
                accP[i][j] = __builtin_amdgcn_mfma_f32_16x16x32_bf16(afr[i], bfr[j], accP[i][j], 0, 0, 0);
    }
    // epilogue + LN1 partials
    float vP[2][2][4];
    float ps[2][4], pq[2][4];
    #pragma unroll
    for (int i = 0; i < 2; i++)
        #pragma unroll
        for (int r = 0; r < 4; r++) { ps[i][r] = 0.f; pq[i][r] = 0.f; }
    #pragma unroll
    for (int i = 0; i < 2; i++) {
        #pragma unroll
        for (int j = 0; j < 2; j++) {
            const int col = n0w + j * 16 + lrow;
            const float bv = bf2f(opb[col]);
            #pragma unroll
            for (int r = 0; r < 4; r++) {
                const int row = i * 16 + quad * 4 + r;
                float v = accP[i][j][r] + bv + bf2f(cx[(size_t)(t0 + row) * 256 + col]);
                vP[i][j][r] = v;
                ps[i][r] += v;
                pq[i][r] += v * v;
            }
        }
    }
    #pragma unroll
    for (int i = 0; i < 2; i++)
        #pragma unroll
        for (int r = 0; r < 4; r++) {
            #pragma unroll
            for (int o = 8; o > 0; o >>= 1) {
                ps[i][r] += __shfl_xor(ps[i][r], o);
                pq[i][r] += __shfl_xor(pq[i][r], o);
            }
            if (lrow == 0) {
                const int row = i * 16 + quad * 4 + r;
                redS[wave * 32 + row] = ps[i][r];
                redQ[wave * 32 + row] = pq[i][r];
            }
        }
    __syncthreads();

    // LN1: y1 -> y1bs (bf16) + y1f kept in registers
    float y1f[2][2][4];
    #pragma unroll
    for (int i = 0; i < 2; i++) {
        #pragma unroll
        for (int r = 0; r < 4; r++) {
            const int row = i * 16 + quad * 4 + r;
            float S = 0.f, Q = 0.f;
            #pragma unroll
            for (int w = 0; w < 8; w++) { S += redS[w * 32 + row]; Q += redQ[w * 32 + row]; }
            const float mean = S * (1.f / 256.f);
            const float var  = Q * (1.f / 256.f) - mean * mean;
            const float rs   = rsqrtf(var + 1e-5f);
            #pragma unroll
            for (int j = 0; j < 2; j++) {
                const int col = n0w + j * 16 + lrow;
                const float o2 = (vP[i][j][r] - mean) * rs * bf2f(ln1g[col]) + bf2f(ln1b[col]);
                y1f[i][j][r] = o2;
                y1bs[row * 264 + col] = f2bf(o2);
            }
        }
    }
    __syncthreads();

    // ---- fc1 (4 col-quarters) + fc2 partial-K accumulate ----
    f32x4 acc2[2][2];
    #pragma unroll
    for (int i = 0; i < 2; i++)
        #pragma unroll
        for (int j = 0; j < 2; j++)
            #pragma unroll
            for (int r = 0; r < 4; r++) acc2[i][j][r] = 0.f;

    for (int q = 0; q < 4; q++) {
        // fc1: out cols q*256 + wave*32 + j*16 + lrow
        f32x4 a1[2][2];
        #pragma unroll
        for (int i = 0; i < 2; i++)
            #pragma unroll
            for (int j = 0; j < 2; j++)
                #pragma unroll
                for (int r = 0; r < 4; r++) a1[i][j][r] = 0.f;
        for (int k0 = 0; k0 < 256; k0 += 32) {
            bf16x8 afr[2], bfr[2];
            #pragma unroll
            for (int i = 0; i < 2; i++)
                afr[i] = *(const bf16x8*)&y1bs[(i * 16 + lrow) * 264 + k0 + quad * 8];
            #pragma unroll
            for (int j = 0; j < 2; j++)
                bfr[j] = *(const bf16x8*)(f1w + (size_t)(q * 256 + n0w + j * 16 + lrow) * 256 + k0 + quad * 8);
            #pragma unroll
            for (int i = 0; i < 2; i++)
                #pragma unroll
                for (int j = 0; j < 2; j++)
                    a1[i][j] = __builtin_amdgcn_mfma_f32_16x16x32_bf16(afr[i], bfr[j], a1[i][j], 0, 0, 0);
        }
        #pragma unroll
        for (int i = 0; i < 2; i++)
            #pragma unroll
            for (int j = 0; j < 2; j++) {
                const int qc = n0w + j * 16 + lrow;            // col within quarter
                const float bv = bf2f(f1b[q * 256 + qc]);
                #pragma unroll
                for (int r = 0; r < 4; r++) {
                    const int row = i * 16 + quad * 4 + r;
                    f1q[row * 260 + qc] = f2bf(gelu_f(a1[i][j][r] + bv));
                }
            }
        __syncthreads();
        // fc2 partial: K-range q*256 .. q*256+256
        for (int k0 = 0; k0 < 256; k0 += 32) {
            bf16x8 afr[2], bfr[2];
            #pragma unroll
            for (int i = 0; i < 2; i++)
                afr[i] = *(const bf16x8*)&f1q[(i * 16 + lrow) * 260 + k0 + quad * 8];
            #pragma unroll
            for (int j = 0; j < 2; j++)
                bfr[j] = *(const bf16x8*)(f2w + (size_t)(n0w + j * 16 + lrow) * 1024 + q * 256 + k0 + quad * 8);
            #pragma unroll
            for (int i = 0; i < 2; i++)
                #pragma unroll
                for (int j = 0; j < 2; j++)
                    acc2[i][j] = __builtin_amdgcn_mfma_f32_16x16x32_bf16(afr[i], bfr[j], acc2[i][j], 0, 0, 0);
        }
        __syncthreads();
    }

    // ---- fc2 epilogue: gelu + resid y1f, LN2, write d_out ----
    float v2[2][2][4];
    #pragma unroll
    for (int i = 0; i < 2; i++)
        #pragma unroll
        for (int r = 0; r < 4; r++) { ps[i][r] = 0.f; pq[i][r] = 0.f; }
    #pragma unroll
    for (int i = 0; i < 2; i++)
        #pragma unroll
        for (int j = 0; j < 2; j++) {
            const int col = n0w + j * 16 + lrow;
            const float bv = bf2f(f2b[col]);
            #pragma unroll
            for (int r = 0; r < 4; r++) {
                const float v = gelu_f(acc2[i][j][r] + bv) + y1f[i][j][r];
                v2[i][j][r] = v;
                ps[i][r] += v;
                pq[i][r] += v * v;
            }
        }
    #pragma unroll
    for (int i = 0; i < 2; i++)
        #pragma unroll
        for (int r = 0; r < 4; r++) {
            #pragma unroll
            for (int o = 8; o > 0; o >>= 1) {
                ps[i][r] += __shfl_xor(ps[i][r], o);
                pq[i][r] += __shfl_xor(pq[i][r], o);
            }
            if (lrow == 0) {
                const int row = i * 16 + quad * 4 + r;
                redS[wave * 32 + row] = ps[i][r];
                redQ[wave * 32 + row] = pq[i][r];
            }
        }
    __syncthreads();

    const bool fl = sniff_inline(sniffx);
    #pragma unroll
    for (int i = 0; i < 2; i++) {
        #pragma unroll
        for (int r = 0; r < 4; r++) {
            const int row = i * 16 + quad * 4 + r;
            float S = 0.f, Q = 0.f;
            #pragma unroll
            for (int w = 0; w < 8; w++) { S += redS[w * 32 + row]; Q += redQ[w * 32 + row]; }
            const float mean = S * (1.f / 256.f);
            const float var  = Q * (1.f / 256.f) - mean * mean;
            const float rs   = rsqrtf(var + 1e-5f);
            #pragma unroll
            for (int j = 0; j < 2; j++) {
                const int col = n0w + j * 16 + lrow;
                const size_t off = (size_t)(t0 + row) * 256 + col;
                const float o2 = (v2[i][j][r] - mean) * rs * bf2f(ln2g[col]) + bf2f(ln2b[col]);
                if (fl) ((ushort*)dout)[off] = f2bf(o2);
                else    ((float*)dout)[off]  = o2;
            }
        }
    }
}

// ---------------------------------------------------------------------------
extern "C" void kernel_launch(void* const* d_in, const int* in_sizes, int n_in,
                              void* d_out, int out_size, void* d_ws, size_t ws_size,
                              hipStream_t stream)
{
    char* ws = (char*)d_ws;
    ushort* canon = (ushort*)(ws + 256);

    static const int coff[20] = {
        0,        2097152,  2359296,  2360320,  2362368,
        2362880,  2387456,  2395648,  2396160,  2404352,
        2404864,  2535936,  2536192,  2536448,  2536704,
        2798848,  2799872,  3062016,  3062272,  3062528 };
    static const int ctot = 3062784;

    CanonArgs ca;
    for (int i = 0; i < 20; i++) { ca.src[i] = d_in[i]; ca.off[i] = coff[i]; }
    ca.total = ctot;

    const ushort* cx   = canon + coff[0];
    const ushort* cipw = canon + coff[1];
    const ushort* cipb = canon + coff[2];
    const ushort* ccw  = canon + coff[3];
    const ushort* ccb  = canon + coff[4];
    const ushort* cdtw = canon + coff[6];
    const ushort* cdtb = canon + coff[7];
    const ushort* calog= canon + coff[8];
    const ushort* cdssm= canon + coff[9];
    const ushort* copw = canon + coff[10];
    const ushort* copb = canon + coff[11];
    const ushort* cln1g= canon + coff[12];
    const ushort* cln1b= canon + coff[13];
    const ushort* cf1w = canon + coff[14];
    const ushort* cf1b = canon + coff[15];
    const ushort* cf2w = canon + coff[16];
    const ushort* cf2b = canon + coff[17];
    const ushort* cln2g= canon + coff[18];
    const ushort* cln2b= canon + coff[19];

    ushort* xpw_pad = (ushort*)(ws + 6291456);  // [64,512] bf16
    ushort* xz      = (ushort*)(ws + 8388608);  // [8192,1024] bf16, 16 MB
    float*  xdbl    = (float*)(ws + 25165824);  // [8192,64] f32, 2 MB
    float*  summ    = (float*)(ws + 27262976);  // [4,64,32,512] f32, 16 MB
    const ushort* sx = (const ushort*)d_in[0];

    // 1. canon + xpw padding
    canon_k<<<(ctot + 8192 + 255) / 256, 256, 0, stream>>>(ca, canon, xpw_pad, sx);
    // 2. in_proj: xz = x @ ipw^T + ipb
    gemm_bt<128, 128><<<dim3(64, 8), 256, 0, stream>>>(cx, cipw, cipb, xz, 1024, 256);
    // 3. conv + silu + xdbl + scan1 (fused)
    convscan1_k<<<dim3(64, 4), 512, 0, stream>>>(
        xz, ccw, ccb, xpw_pad, cdtw, cdtb, calog, xdbl, summ);
    // 4. combine (chunk-boundary states)
    combine_k<<<64, 512, 0, stream>>>(summ);
    // 5. tail: scan2 + out_proj + LN1 + fc1 + fc2 + LN2 -> d_out
    tail_k<<<dim3(64, 4), 512, 0, stream>>>(
        xz, ccw, ccb, xdbl, cdtw, cdtb, calog, summ, cdssm, cx,
        copw, copb, cln1g, cln1b, cf1w, cf1b, cf2w, cf2b, cln2g, cln2b,
        d_out, sx);
}